// Round 1
// baseline (465.677 us; speedup 1.0000x reference)
//
#include <hip/hip_runtime.h>
#include <hip/hip_bf16.h>

#define N_NODES 50000
#define N_EDGE  800000
#define ET      850000          // N_EDGE + N_NODES self loops
#define IN_DIM  256
#define F1      128             // H1*C1
#define NHEAD   4
#define C1      32
#define OUT_C   40
#define NEG     0.2f

// ---------------- graph build ----------------
__global__ void k_init(int* cnt, int* cursor) {
    int i = blockIdx.x * 256 + threadIdx.x;
    if (i < N_NODES) { cnt[i] = 1; cursor[i] = 0; }   // 1 = self loop
}

__global__ void k_deg(const int* __restrict__ eidx, int* cnt) {
    int e = blockIdx.x * 256 + threadIdx.x;
    if (e < N_EDGE) atomicAdd(&cnt[eidx[N_EDGE + e]], 1);
}

__global__ void k_scan1(const int* __restrict__ cnt, int* rowptr, int* bsums) {
    __shared__ int sh[256];
    int t = threadIdx.x;
    int i = blockIdx.x * 256 + t;
    int v = (i < N_NODES) ? cnt[i] : 0;
    sh[t] = v; __syncthreads();
    for (int off = 1; off < 256; off <<= 1) {
        int x = (t >= off) ? sh[t - off] : 0;
        __syncthreads();
        sh[t] += x;
        __syncthreads();
    }
    if (i < N_NODES) rowptr[i] = sh[t] - v;      // exclusive
    if (t == 255) bsums[blockIdx.x] = sh[t];     // block total
}

__global__ void k_scan2(int* bsums) {
    __shared__ int sh[256];
    int t = threadIdx.x;
    int v = (t < 196) ? bsums[t] : 0;
    sh[t] = v; __syncthreads();
    for (int off = 1; off < 256; off <<= 1) {
        int x = (t >= off) ? sh[t - off] : 0;
        __syncthreads();
        sh[t] += x;
        __syncthreads();
    }
    if (t < 196) bsums[t] = sh[t] - v;           // exclusive
}

__global__ void k_scan3(int* rowptr, const int* __restrict__ bsums) {
    int i = blockIdx.x * 256 + threadIdx.x;
    if (i < N_NODES) rowptr[i] += bsums[blockIdx.x];
    if (i == 0) rowptr[N_NODES] = ET;
}

__global__ void k_scatter(const int* __restrict__ eidx, const int* __restrict__ rowptr,
                          int* cursor, int* esrc) {
    int e = blockIdx.x * 256 + threadIdx.x;
    if (e >= ET) return;
    int s, d;
    if (e < N_EDGE) { s = eidx[e]; d = eidx[N_EDGE + e]; }
    else            { s = e - N_EDGE; d = s; }
    int pos = rowptr[d] + atomicAdd(&cursor[d], 1);
    esrc[pos] = s;
}

// ---------------- layer 1 GEMM (+ fused attention logits) ----------------
__global__ __launch_bounds__(256) void k_gemm1(
        const float* __restrict__ x, const float* __restrict__ W1,
        const float* __restrict__ a_src1, const float* __restrict__ a_dst1,
        float* __restrict__ h1, float* __restrict__ als1, float* __restrict__ ald1) {
    __shared__ float xsT[32][68];    // [k][row], padded
    __shared__ float ws[32][128];    // [k][col]
    int t  = threadIdx.x;
    int r0 = blockIdx.x * 64;
    int rg = t >> 5;                 // row group 0..7  (rows rg*8 .. rg*8+7)
    int cl = t & 31;                 // col group       (cols cl*4 .. cl*4+3)
    float acc[8][4] = {};

    for (int kc = 0; kc < IN_DIM; kc += 32) {
#pragma unroll
        for (int i = 0; i < 8; i++) {            // 64x32 A tile, stored transposed
            int idx = i * 256 + t;
            int row = idx >> 5, col = idx & 31;
            int gr = r0 + row;
            xsT[col][row] = (gr < N_NODES) ? x[(size_t)gr * IN_DIM + kc + col] : 0.f;
        }
#pragma unroll
        for (int i = 0; i < 16; i++) {           // 32x128 B tile
            int idx = i * 256 + t;
            int kr = idx >> 7, col = idx & 127;
            ws[kr][col] = W1[(kc + kr) * F1 + col];
        }
        __syncthreads();
#pragma unroll
        for (int kk = 0; kk < 32; kk++) {
            float4 b  = *(const float4*)&ws[kk][cl * 4];
            float4 a0 = *(const float4*)&xsT[kk][rg * 8];
            float4 a1 = *(const float4*)&xsT[kk][rg * 8 + 4];
            float av[8] = {a0.x, a0.y, a0.z, a0.w, a1.x, a1.y, a1.z, a1.w};
#pragma unroll
            for (int i = 0; i < 8; i++) {
                acc[i][0] += av[i] * b.x; acc[i][1] += av[i] * b.y;
                acc[i][2] += av[i] * b.z; acc[i][3] += av[i] * b.w;
            }
        }
        __syncthreads();
    }

    float4 as4 = *(const float4*)&a_src1[cl * 4];
    float4 ad4 = *(const float4*)&a_dst1[cl * 4];
    int head = cl >> 3;              // cols cl*4.. belong to head cl/8
#pragma unroll
    for (int i = 0; i < 8; i++) {
        int r = r0 + rg * 8 + i;
        if (r < N_NODES) {
            *(float4*)&h1[(size_t)r * F1 + cl * 4] =
                make_float4(acc[i][0], acc[i][1], acc[i][2], acc[i][3]);
        }
        float ps = acc[i][0]*as4.x + acc[i][1]*as4.y + acc[i][2]*as4.z + acc[i][3]*as4.w;
        float pd = acc[i][0]*ad4.x + acc[i][1]*ad4.y + acc[i][2]*ad4.z + acc[i][3]*ad4.w;
        ps += __shfl_xor(ps, 1); ps += __shfl_xor(ps, 2); ps += __shfl_xor(ps, 4);
        pd += __shfl_xor(pd, 1); pd += __shfl_xor(pd, 2); pd += __shfl_xor(pd, 4);
        if ((cl & 7) == 0 && r < N_NODES) {
            als1[r * NHEAD + head] = ps;
            ald1[r * NHEAD + head] = pd;
        }
    }
}

// ---------------- layer 1 softmax (max + expsum) ----------------
__global__ void k_ms1(const int* __restrict__ rowptr, const int* __restrict__ esrc,
                      const float* __restrict__ als1, const float* __restrict__ ald1,
                      float* __restrict__ p1, float* __restrict__ ss1) {
    int tid = blockIdx.x * 256 + threadIdx.x;
    if (tid >= N_NODES * NHEAD) return;
    int n = tid >> 2, h = tid & 3;
    int b = rowptr[n], e = rowptr[n + 1];
    float ad = ald1[n * NHEAD + h];
    float m = -1e30f;
    for (int j = b; j < e; j++) {
        float v = als1[esrc[j] * NHEAD + h] + ad;
        v = (v > 0.f) ? v : NEG * v;
        m = fmaxf(m, v);
    }
    float s = 0.f;
    for (int j = b; j < e; j++) {
        float v = als1[esrc[j] * NHEAD + h] + ad;
        v = (v > 0.f) ? v : NEG * v;
        float p = __expf(v - m);
        p1[(size_t)j * NHEAD + h] = p;
        s += p;
    }
    ss1[n * NHEAD + h] = 1.f / s;
}

// ---------------- layer 1 aggregation + bias + ELU ----------------
__global__ __launch_bounds__(128) void k_agg1(
        const int* __restrict__ rowptr, const int* __restrict__ esrc,
        const float* __restrict__ p1, const float* __restrict__ ss1,
        const float* __restrict__ h1, const float* __restrict__ b1,
        float* __restrict__ h1out) {
    __shared__ int   s_src[64];
    __shared__ float s_p[64][4];
    int n = blockIdx.x;
    int t = threadIdx.x;
    int b = rowptr[n], e = rowptr[n + 1];
    int h = t >> 5;
    float acc = 0.f;
    for (int base = b; base < e; base += 64) {
        int cnt = min(64, e - base);
        if (t < cnt) s_src[t] = esrc[base + t];
        for (int i = t; i < cnt * 4; i += 128)
            s_p[i >> 2][i & 3] = p1[(size_t)base * 4 + i];
        __syncthreads();
        for (int j = 0; j < cnt; j++)
            acc += s_p[j][h] * h1[(size_t)s_src[j] * F1 + t];
        __syncthreads();
    }
    float v = acc * ss1[n * NHEAD + h] + b1[t];
    v = (v > 0.f) ? v : (__expf(v) - 1.f);      // ELU
    h1out[(size_t)n * F1 + t] = v;
}

// ---------------- layer 2 GEMM (+ fused logits) ----------------
__global__ __launch_bounds__(256) void k_gemm2(
        const float* __restrict__ h1out, const float* __restrict__ W2,
        const float* __restrict__ a_src2, const float* __restrict__ a_dst2,
        float* __restrict__ h2, float* __restrict__ als2, float* __restrict__ ald2) {
    __shared__ float hs[64][129];
    __shared__ float w2s[128][40];
    int t = threadIdx.x;
    int r0 = blockIdx.x * 64;
    for (int i = t; i < F1 * OUT_C; i += 256) w2s[i / 40][i % 40] = W2[i];
    for (int i = t; i < 64 * F1; i += 256) {
        int row = i >> 7, col = i & 127;
        int gr = r0 + row;
        hs[row][col] = (gr < N_NODES) ? h1out[(size_t)gr * F1 + col] : 0.f;
    }
    __syncthreads();
    int row = t >> 2;
    int cb  = (t & 3) * 10;
    float acc[10] = {};
    for (int k = 0; k < F1; k++) {
        float a = hs[row][k];
#pragma unroll
        for (int i = 0; i < 10; i++) acc[i] += a * w2s[k][cb + i];
    }
    int gr = r0 + row;
    float ps = 0.f, pd = 0.f;
#pragma unroll
    for (int i = 0; i < 10; i++) {
        ps += acc[i] * a_src2[cb + i];
        pd += acc[i] * a_dst2[cb + i];
    }
    ps += __shfl_xor(ps, 1); ps += __shfl_xor(ps, 2);
    pd += __shfl_xor(pd, 1); pd += __shfl_xor(pd, 2);
    if ((t & 3) == 0 && gr < N_NODES) { als2[gr] = ps; ald2[gr] = pd; }
    if (gr < N_NODES) {
#pragma unroll
        for (int i = 0; i < 10; i++) h2[(size_t)gr * OUT_C + cb + i] = acc[i];
    }
}

// ---------------- layer 2 softmax ----------------
__global__ void k_ms2(const int* __restrict__ rowptr, const int* __restrict__ esrc,
                      const float* __restrict__ als2, const float* __restrict__ ald2,
                      float* __restrict__ p2, float* __restrict__ ss2) {
    int n = blockIdx.x * 256 + threadIdx.x;
    if (n >= N_NODES) return;
    int b = rowptr[n], e = rowptr[n + 1];
    float ad = ald2[n];
    float m = -1e30f;
    for (int j = b; j < e; j++) {
        float v = als2[esrc[j]] + ad;
        v = (v > 0.f) ? v : NEG * v;
        m = fmaxf(m, v);
    }
    float s = 0.f;
    for (int j = b; j < e; j++) {
        float v = als2[esrc[j]] + ad;
        v = (v > 0.f) ? v : NEG * v;
        float p = __expf(v - m);
        p2[j] = p;
        s += p;
    }
    ss2[n] = 1.f / s;
}

// ---------------- layer 2 aggregation + bias + log_softmax ----------------
__global__ __launch_bounds__(256) void k_agg2(
        const int* __restrict__ rowptr, const int* __restrict__ esrc,
        const float* __restrict__ p2, const float* __restrict__ ss2,
        const float* __restrict__ h2, const float* __restrict__ b2,
        float* __restrict__ out) {
    int wv = threadIdx.x >> 6;
    int ln = threadIdx.x & 63;
    int n = blockIdx.x * 4 + wv;
    if (n >= N_NODES) return;
    int b = rowptr[n], e = rowptr[n + 1];
    float acc = 0.f;
    for (int base = b; base < e; base += 64) {
        int cnt = min(64, e - base);
        int s_reg = 0; float p_reg = 0.f;
        if (ln < cnt) { s_reg = esrc[base + ln]; p_reg = p2[base + ln]; }
        for (int j = 0; j < cnt; j++) {
            int   s = __shfl(s_reg, j);
            float p = __shfl(p_reg, j);
            if (ln < OUT_C) acc += p * h2[(size_t)s * OUT_C + ln];
        }
    }
    float y = (ln < OUT_C) ? acc * ss2[n] + b2[ln] : -1e30f;
    float m = y;
    for (int off = 1; off < 64; off <<= 1) m = fmaxf(m, __shfl_xor(m, off));
    float z = (ln < OUT_C) ? __expf(y - m) : 0.f;
    float sm = z;
    for (int off = 1; off < 64; off <<= 1) sm += __shfl_xor(sm, off);
    if (ln < OUT_C) out[(size_t)n * OUT_C + ln] = y - m - logf(sm);
}

extern "C" void kernel_launch(void* const* d_in, const int* in_sizes, int n_in,
                              void* d_out, int out_size, void* d_ws, size_t ws_size,
                              hipStream_t stream) {
    const float* x      = (const float*)d_in[0];
    const int*   eidx   = (const int*)d_in[1];
    const float* W1     = (const float*)d_in[2];
    const float* a_src1 = (const float*)d_in[3];
    const float* a_dst1 = (const float*)d_in[4];
    const float* b1     = (const float*)d_in[5];
    const float* W2     = (const float*)d_in[6];
    const float* a_src2 = (const float*)d_in[7];
    const float* a_dst2 = (const float*)d_in[8];
    const float* b2     = (const float*)d_in[9];
    float* out = (float*)d_out;

    // workspace layout (floats then ints), ~83 MB total
    float* wf    = (float*)d_ws;
    float* h1    = wf;                   // 6,400,000
    float* h1out = wf + 6400000;         // 6,400,000
    float* p1    = wf + 12800000;        // 3,400,000
    float* h2    = wf + 16200000;        // 2,000,000
    float* als1  = wf + 18200000;        // 200,000
    float* ald1  = wf + 18400000;        // 200,000
    float* ss1   = wf + 18600000;        // 200,000
    float* als2  = wf + 18800000;        // 50,000
    float* ald2  = wf + 18850000;        // 50,000
    float* ss2   = wf + 18900000;        // 50,000
    float* p2    = wf + 18950000;        // 850,000
    int* ip      = (int*)(wf + 19800000);
    int* rowptr  = ip;                   // 50,001
    int* cnt     = ip + 50001;           // 50,000
    int* cursor  = ip + 100001;          // 50,000
    int* esrc    = ip + 150001;          // 850,000
    int* bsums   = ip + 1000001;         // 256

    // graph build
    k_init   <<<196, 256, 0, stream>>>(cnt, cursor);
    k_deg    <<<(N_EDGE + 255) / 256, 256, 0, stream>>>(eidx, cnt);
    k_scan1  <<<196, 256, 0, stream>>>(cnt, rowptr, bsums);
    k_scan2  <<<1, 256, 0, stream>>>(bsums);
    k_scan3  <<<196, 256, 0, stream>>>(rowptr, bsums);
    k_scatter<<<(ET + 255) / 256, 256, 0, stream>>>(eidx, rowptr, cursor, esrc);

    // layer 1
    k_gemm1<<<(N_NODES + 63) / 64, 256, 0, stream>>>(x, W1, a_src1, a_dst1, h1, als1, ald1);
    k_ms1  <<<(N_NODES * NHEAD + 255) / 256, 256, 0, stream>>>(rowptr, esrc, als1, ald1, p1, ss1);
    k_agg1 <<<N_NODES, 128, 0, stream>>>(rowptr, esrc, p1, ss1, h1, b1, h1out);

    // layer 2
    k_gemm2<<<(N_NODES + 63) / 64, 256, 0, stream>>>(h1out, W2, a_src2, a_dst2, h2, als2, ald2);
    k_ms2  <<<(N_NODES + 255) / 256, 256, 0, stream>>>(rowptr, esrc, als2, ald2, p2, ss2);
    k_agg2 <<<(N_NODES + 3) / 4, 256, 0, stream>>>(rowptr, esrc, p2, ss2, h2, b2, out);
}

// Round 2
// 418.776 us; speedup vs baseline: 1.1120x; 1.1120x over previous
//
#include <hip/hip_runtime.h>
#include <hip/hip_bf16.h>

#define N_NODES 50000
#define N_EDGE  800000
#define ET      850000          // N_EDGE + N_NODES self loops
#define IN_DIM  256
#define F1      128             // H1*C1
#define NHEAD   4
#define C1      32
#define OUT_C   40
#define NEG     0.2f

typedef __bf16 bf16_8 __attribute__((ext_vector_type(8)));
typedef float  f32x4  __attribute__((ext_vector_type(4)));

static __device__ __forceinline__ ushort f2b(float f) {
    __hip_bfloat16 h = __float2bfloat16(f);
    return *reinterpret_cast<ushort*>(&h);
}

// ---------------- graph build ----------------
__global__ void k_init(int* cnt, int* cursor) {
    int i = blockIdx.x * 256 + threadIdx.x;
    if (i < N_NODES) { cnt[i] = 1; cursor[i] = 0; }   // 1 = self loop
}

__global__ void k_deg(const int* __restrict__ eidx, int* cnt) {
    int e = blockIdx.x * 256 + threadIdx.x;
    if (e < N_EDGE) atomicAdd(&cnt[eidx[N_EDGE + e]], 1);
}

__global__ void k_scan1(const int* __restrict__ cnt, int* rowptr, int* bsums) {
    __shared__ int sh[256];
    int t = threadIdx.x;
    int i = blockIdx.x * 256 + t;
    int v = (i < N_NODES) ? cnt[i] : 0;
    sh[t] = v; __syncthreads();
    for (int off = 1; off < 256; off <<= 1) {
        int x = (t >= off) ? sh[t - off] : 0;
        __syncthreads();
        sh[t] += x;
        __syncthreads();
    }
    if (i < N_NODES) rowptr[i] = sh[t] - v;      // exclusive
    if (t == 255) bsums[blockIdx.x] = sh[t];     // block total
}

__global__ void k_scan2(int* bsums) {
    __shared__ int sh[256];
    int t = threadIdx.x;
    int v = (t < 196) ? bsums[t] : 0;
    sh[t] = v; __syncthreads();
    for (int off = 1; off < 256; off <<= 1) {
        int x = (t >= off) ? sh[t - off] : 0;
        __syncthreads();
        sh[t] += x;
        __syncthreads();
    }
    if (t < 196) bsums[t] = sh[t] - v;           // exclusive
}

__global__ void k_scan3(int* rowptr, const int* __restrict__ bsums) {
    int i = blockIdx.x * 256 + threadIdx.x;
    if (i < N_NODES) rowptr[i] += bsums[blockIdx.x];
    if (i == 0) rowptr[N_NODES] = ET;
}

__global__ void k_scatter(const int* __restrict__ eidx, const int* __restrict__ rowptr,
                          int* cursor, int* esrc) {
    int e = blockIdx.x * 256 + threadIdx.x;
    if (e >= ET) return;
    int s, d;
    if (e < N_EDGE) { s = eidx[e]; d = eidx[N_EDGE + e]; }
    else            { s = e - N_EDGE; d = s; }
    int pos = rowptr[d] + atomicAdd(&cursor[d], 1);
    esrc[pos] = s;
}

// ---------------- prep: W1 -> bf16 transposed [n][k] ----------------
__global__ void k_prepW1(const float* __restrict__ W1, ushort* __restrict__ W1T) {
    int i = blockIdx.x * 256 + threadIdx.x;      // i = n*256 + k
    if (i >= F1 * IN_DIM) return;
    int n = i >> 8, k = i & 255;
    W1T[i] = f2b(W1[k * F1 + n]);
}

// ---------------- layer 1 GEMM via MFMA (+ fused attention logits) ----------------
// block: 256 thr = 4 waves; tile 64 rows x 128 cols; wave w -> rows w*16..+15
__global__ __launch_bounds__(256) void k_gemm1m(
        const float* __restrict__ x, const ushort* __restrict__ W1T,
        const float* __restrict__ a_src1, const float* __restrict__ a_dst1,
        float* __restrict__ h1, float* __restrict__ als1, float* __restrict__ ald1) {
    __shared__ ushort As[64 * 40];   // [row][k], pad 32->40 to break bank stride
    __shared__ ushort Bs[128 * 40];  // [n][k]
    int t = threadIdx.x;
    int w = t >> 6, lane = t & 63;
    int cl = lane & 15, q = lane >> 4;
    int r0 = blockIdx.x * 64;

    f32x4 acc[8];
#pragma unroll
    for (int i = 0; i < 8; i++) acc[i] = (f32x4){0.f, 0.f, 0.f, 0.f};

    int arow = t >> 2;               // A staging: row, 8 consecutive k
    int akp  = (t & 3) * 8;
    int brow = t >> 1;               // B staging: n, 16 consecutive k
    int bkp  = (t & 1) * 16;
    int agr  = r0 + arow;

    for (int kc = 0; kc < IN_DIM; kc += 32) {
        float4 f0, f1;
        if (agr < N_NODES) {
            f0 = *(const float4*)&x[(size_t)agr * IN_DIM + kc + akp];
            f1 = *(const float4*)&x[(size_t)agr * IN_DIM + kc + akp + 4];
        } else {
            f0 = make_float4(0.f, 0.f, 0.f, 0.f);
            f1 = f0;
        }
        ushort4 u0 = {f2b(f0.x), f2b(f0.y), f2b(f0.z), f2b(f0.w)};
        ushort4 u1 = {f2b(f1.x), f2b(f1.y), f2b(f1.z), f2b(f1.w)};
        *(ushort4*)&As[arow * 40 + akp]     = u0;
        *(ushort4*)&As[arow * 40 + akp + 4] = u1;

        *(uint4*)&Bs[brow * 40 + bkp]     = *(const uint4*)&W1T[brow * IN_DIM + kc + bkp];
        *(uint4*)&Bs[brow * 40 + bkp + 8] = *(const uint4*)&W1T[brow * IN_DIM + kc + bkp + 8];
        __syncthreads();

        bf16_8 af = *(bf16_8*)&As[(w * 16 + cl) * 40 + q * 8];
#pragma unroll
        for (int ct = 0; ct < 8; ct++) {
            bf16_8 bfr = *(bf16_8*)&Bs[(ct * 16 + cl) * 40 + q * 8];
            acc[ct] = __builtin_amdgcn_mfma_f32_16x16x32_bf16(af, bfr, acc[ct], 0, 0, 0);
        }
        __syncthreads();
    }

    float asv[8], adv[8];
#pragma unroll
    for (int ct = 0; ct < 8; ct++) {
        asv[ct] = a_src1[ct * 16 + cl];
        adv[ct] = a_dst1[ct * 16 + cl];
    }

#pragma unroll
    for (int reg = 0; reg < 4; reg++) {
        int grow = r0 + w * 16 + q * 4 + reg;
        bool ok = grow < N_NODES;
        float ps[4] = {0.f, 0.f, 0.f, 0.f};
        float pd[4] = {0.f, 0.f, 0.f, 0.f};
#pragma unroll
        for (int ct = 0; ct < 8; ct++) {
            float v = acc[ct][reg];
            if (ok) h1[(size_t)grow * F1 + ct * 16 + cl] = v;
            ps[ct >> 1] += v * asv[ct];
            pd[ct >> 1] += v * adv[ct];
        }
#pragma unroll
        for (int hh = 0; hh < 4; hh++) {
            ps[hh] += __shfl_xor(ps[hh], 1); ps[hh] += __shfl_xor(ps[hh], 2);
            ps[hh] += __shfl_xor(ps[hh], 4); ps[hh] += __shfl_xor(ps[hh], 8);
            pd[hh] += __shfl_xor(pd[hh], 1); pd[hh] += __shfl_xor(pd[hh], 2);
            pd[hh] += __shfl_xor(pd[hh], 4); pd[hh] += __shfl_xor(pd[hh], 8);
        }
        if (cl == 0 && ok) {
#pragma unroll
            for (int hh = 0; hh < 4; hh++) {
                als1[grow * NHEAD + hh] = ps[hh];
                ald1[grow * NHEAD + hh] = pd[hh];
            }
        }
    }
}

// ---------------- layer 1 softmax (max + expsum) ----------------
__global__ void k_ms1(const int* __restrict__ rowptr, const int* __restrict__ esrc,
                      const float* __restrict__ als1, const float* __restrict__ ald1,
                      float* __restrict__ p1, float* __restrict__ ss1) {
    int tid = blockIdx.x * 256 + threadIdx.x;
    if (tid >= N_NODES * NHEAD) return;
    int n = tid >> 2, h = tid & 3;
    int b = rowptr[n], e = rowptr[n + 1];
    float ad = ald1[n * NHEAD + h];
    float m = -1e30f;
    for (int j = b; j < e; j++) {
        float v = als1[esrc[j] * NHEAD + h] + ad;
        v = (v > 0.f) ? v : NEG * v;
        m = fmaxf(m, v);
    }
    float s = 0.f;
    for (int j = b; j < e; j++) {
        float v = als1[esrc[j] * NHEAD + h] + ad;
        v = (v > 0.f) ? v : NEG * v;
        float p = __expf(v - m);
        p1[(size_t)j * NHEAD + h] = p;
        s += p;
    }
    ss1[n * NHEAD + h] = 1.f / s;
}

// ---------------- layer 1 aggregation + bias + ELU ----------------
__global__ __launch_bounds__(128) void k_agg1(
        const int* __restrict__ rowptr, const int* __restrict__ esrc,
        const float* __restrict__ p1, const float* __restrict__ ss1,
        const float* __restrict__ h1, const float* __restrict__ b1,
        float* __restrict__ h1out) {
    __shared__ int   s_src[64];
    __shared__ float s_p[64][4];
    int n = blockIdx.x;
    int t = threadIdx.x;
    int b = rowptr[n], e = rowptr[n + 1];
    int h = t >> 5;
    float acc = 0.f;
    for (int base = b; base < e; base += 64) {
        int cnt = min(64, e - base);
        if (t < cnt) s_src[t] = esrc[base + t];
        for (int i = t; i < cnt * 4; i += 128)
            s_p[i >> 2][i & 3] = p1[(size_t)base * 4 + i];
        __syncthreads();
        for (int j = 0; j < cnt; j++)
            acc += s_p[j][h] * h1[(size_t)s_src[j] * F1 + t];
        __syncthreads();
    }
    float v = acc * ss1[n * NHEAD + h] + b1[t];
    v = (v > 0.f) ? v : (__expf(v) - 1.f);      // ELU
    h1out[(size_t)n * F1 + t] = v;
}

// ---------------- layer 2 GEMM (+ fused logits) ----------------
__global__ __launch_bounds__(256) void k_gemm2(
        const float* __restrict__ h1out, const float* __restrict__ W2,
        const float* __restrict__ a_src2, const float* __restrict__ a_dst2,
        float* __restrict__ h2, float* __restrict__ als2, float* __restrict__ ald2) {
    __shared__ float hs[64][129];
    __shared__ float w2s[128][40];
    int t = threadIdx.x;
    int r0 = blockIdx.x * 64;
    for (int i = t; i < F1 * OUT_C; i += 256) w2s[i / 40][i % 40] = W2[i];
    for (int i = t; i < 64 * F1; i += 256) {
        int row = i >> 7, col = i & 127;
        int gr = r0 + row;
        hs[row][col] = (gr < N_NODES) ? h1out[(size_t)gr * F1 + col] : 0.f;
    }
    __syncthreads();
    int row = t >> 2;
    int cb  = (t & 3) * 10;
    float acc[10] = {};
    for (int k = 0; k < F1; k++) {
        float a = hs[row][k];
#pragma unroll
        for (int i = 0; i < 10; i++) acc[i] += a * w2s[k][cb + i];
    }
    int gr = r0 + row;
    float ps = 0.f, pd = 0.f;
#pragma unroll
    for (int i = 0; i < 10; i++) {
        ps += acc[i] * a_src2[cb + i];
        pd += acc[i] * a_dst2[cb + i];
    }
    ps += __shfl_xor(ps, 1); ps += __shfl_xor(ps, 2);
    pd += __shfl_xor(pd, 1); pd += __shfl_xor(pd, 2);
    if ((t & 3) == 0 && gr < N_NODES) { als2[gr] = ps; ald2[gr] = pd; }
    if (gr < N_NODES) {
#pragma unroll
        for (int i = 0; i < 10; i++) h2[(size_t)gr * OUT_C + cb + i] = acc[i];
    }
}

// ---------------- layer 2 softmax ----------------
__global__ void k_ms2(const int* __restrict__ rowptr, const int* __restrict__ esrc,
                      const float* __restrict__ als2, const float* __restrict__ ald2,
                      float* __restrict__ p2, float* __restrict__ ss2) {
    int n = blockIdx.x * 256 + threadIdx.x;
    if (n >= N_NODES) return;
    int b = rowptr[n], e = rowptr[n + 1];
    float ad = ald2[n];
    float m = -1e30f;
    for (int j = b; j < e; j++) {
        float v = als2[esrc[j]] + ad;
        v = (v > 0.f) ? v : NEG * v;
        m = fmaxf(m, v);
    }
    float s = 0.f;
    for (int j = b; j < e; j++) {
        float v = als2[esrc[j]] + ad;
        v = (v > 0.f) ? v : NEG * v;
        float p = __expf(v - m);
        p2[j] = p;
        s += p;
    }
    ss2[n] = 1.f / s;
}

// ---------------- layer 2 aggregation + bias + log_softmax ----------------
__global__ __launch_bounds__(256) void k_agg2(
        const int* __restrict__ rowptr, const int* __restrict__ esrc,
        const float* __restrict__ p2, const float* __restrict__ ss2,
        const float* __restrict__ h2, const float* __restrict__ b2,
        float* __restrict__ out) {
    int wv = threadIdx.x >> 6;
    int ln = threadIdx.x & 63;
    int n = blockIdx.x * 4 + wv;
    if (n >= N_NODES) return;
    int b = rowptr[n], e = rowptr[n + 1];
    float acc = 0.f;
    for (int base = b; base < e; base += 64) {
        int cnt = min(64, e - base);
        int s_reg = 0; float p_reg = 0.f;
        if (ln < cnt) { s_reg = esrc[base + ln]; p_reg = p2[base + ln]; }
        for (int j = 0; j < cnt; j++) {
            int   s = __shfl(s_reg, j);
            float p = __shfl(p_reg, j);
            if (ln < OUT_C) acc += p * h2[(size_t)s * OUT_C + ln];
        }
    }
    float y = (ln < OUT_C) ? acc * ss2[n] + b2[ln] : -1e30f;
    float m = y;
    for (int off = 1; off < 64; off <<= 1) m = fmaxf(m, __shfl_xor(m, off));
    float z = (ln < OUT_C) ? __expf(y - m) : 0.f;
    float sm = z;
    for (int off = 1; off < 64; off <<= 1) sm += __shfl_xor(sm, off);
    if (ln < OUT_C) out[(size_t)n * OUT_C + ln] = y - m - logf(sm);
}

extern "C" void kernel_launch(void* const* d_in, const int* in_sizes, int n_in,
                              void* d_out, int out_size, void* d_ws, size_t ws_size,
                              hipStream_t stream) {
    const float* x      = (const float*)d_in[0];
    const int*   eidx   = (const int*)d_in[1];
    const float* W1     = (const float*)d_in[2];
    const float* a_src1 = (const float*)d_in[3];
    const float* a_dst1 = (const float*)d_in[4];
    const float* b1     = (const float*)d_in[5];
    const float* W2     = (const float*)d_in[6];
    const float* a_src2 = (const float*)d_in[7];
    const float* a_dst2 = (const float*)d_in[8];
    const float* b2     = (const float*)d_in[9];
    float* out = (float*)d_out;

    // workspace layout (floats then ints), ~84 MB total
    float* wf    = (float*)d_ws;
    float* h1    = wf;                   // 6,400,000
    float* h1out = wf + 6400000;         // 6,400,000
    float* p1    = wf + 12800000;        // 3,400,000
    float* h2    = wf + 16200000;        // 2,000,000
    float* als1  = wf + 18200000;        // 200,000
    float* ald1  = wf + 18400000;        // 200,000
    float* ss1   = wf + 18600000;        // 200,000
    float* als2  = wf + 18800000;        // 50,000
    float* ald2  = wf + 18850000;        // 50,000
    float* ss2   = wf + 18900000;        // 50,000
    float* p2    = wf + 18950000;        // 850,000
    int* ip      = (int*)(wf + 19800000);
    int* rowptr  = ip;                   // 50,001
    int* cnt     = ip + 50001;           // 50,000
    int* cursor  = ip + 100001;          // 50,000
    int* esrc    = ip + 150001;          // 850,000
    int* bsums   = ip + 1000001;         // 256
    ushort* W1T  = (ushort*)(ip + 1000260); // 32,768 ushorts

    // graph build
    k_init   <<<196, 256, 0, stream>>>(cnt, cursor);
    k_deg    <<<(N_EDGE + 255) / 256, 256, 0, stream>>>(eidx, cnt);
    k_scan1  <<<196, 256, 0, stream>>>(cnt, rowptr, bsums);
    k_scan2  <<<1, 256, 0, stream>>>(bsums);
    k_scan3  <<<196, 256, 0, stream>>>(rowptr, bsums);
    k_scatter<<<(ET + 255) / 256, 256, 0, stream>>>(eidx, rowptr, cursor, esrc);

    // layer 1
    k_prepW1<<<(F1 * IN_DIM + 255) / 256, 256, 0, stream>>>(W1, W1T);
    k_gemm1m<<<(N_NODES + 63) / 64, 256, 0, stream>>>(x, W1T, a_src1, a_dst1, h1, als1, ald1);
    k_ms1  <<<(N_NODES * NHEAD + 255) / 256, 256, 0, stream>>>(rowptr, esrc, als1, ald1, p1, ss1);
    k_agg1 <<<N_NODES, 128, 0, stream>>>(rowptr, esrc, p1, ss1, h1, b1, h1out);

    // layer 2
    k_gemm2<<<(N_NODES + 63) / 64, 256, 0, stream>>>(h1out, W2, a_src2, a_dst2, h2, als2, ald2);
    k_ms2  <<<(N_NODES + 255) / 256, 256, 0, stream>>>(rowptr, esrc, als2, ald2, p2, ss2);
    k_agg2 <<<(N_NODES + 3) / 4, 256, 0, stream>>>(rowptr, esrc, p2, ss2, h2, b2, out);
}

// Round 3
// 379.188 us; speedup vs baseline: 1.2281x; 1.1044x over previous
//
#include <hip/hip_runtime.h>
#include <hip/hip_bf16.h>

#define N_NODES 50000
#define N_EDGE  800000
#define ET      850000          // N_EDGE + N_NODES self loops
#define IN_DIM  256
#define F1      128             // H1*C1
#define NHEAD   4
#define C1      32
#define OUT_C   40
#define NEG     0.2f

typedef __bf16 bf16_8 __attribute__((ext_vector_type(8)));
typedef float  f32x4  __attribute__((ext_vector_type(4)));

static __device__ __forceinline__ ushort f2b(float f) {
    __hip_bfloat16 h = __float2bfloat16(f);
    return *reinterpret_cast<ushort*>(&h);
}
static __device__ __forceinline__ float b2f(ushort u) {
    unsigned v = ((unsigned)u) << 16;
    return __uint_as_float(v);
}
static __device__ __forceinline__ float lrelu(float v) {
    return (v > 0.f) ? v : NEG * v;
}

// ---------------- graph build ----------------
__global__ void k_init(int* cnt, int* cursor) {
    int i = blockIdx.x * 256 + threadIdx.x;
    if (i < N_NODES) { cnt[i] = 1; cursor[i] = 0; }   // 1 = self loop
}

__global__ void k_deg(const int* __restrict__ eidx, int* cnt) {
    int e = blockIdx.x * 256 + threadIdx.x;
    if (e < N_EDGE) atomicAdd(&cnt[eidx[N_EDGE + e]], 1);
}

__global__ void k_scan1(const int* __restrict__ cnt, int* rowptr, int* bsums) {
    __shared__ int sh[256];
    int t = threadIdx.x;
    int i = blockIdx.x * 256 + t;
    int v = (i < N_NODES) ? cnt[i] : 0;
    sh[t] = v; __syncthreads();
    for (int off = 1; off < 256; off <<= 1) {
        int x = (t >= off) ? sh[t - off] : 0;
        __syncthreads();
        sh[t] += x;
        __syncthreads();
    }
    if (i < N_NODES) rowptr[i] = sh[t] - v;      // exclusive
    if (t == 255) bsums[blockIdx.x] = sh[t];     // block total
}

__global__ void k_scan2(int* bsums) {
    __shared__ int sh[256];
    int t = threadIdx.x;
    int v = (t < 196) ? bsums[t] : 0;
    sh[t] = v; __syncthreads();
    for (int off = 1; off < 256; off <<= 1) {
        int x = (t >= off) ? sh[t - off] : 0;
        __syncthreads();
        sh[t] += x;
        __syncthreads();
    }
    if (t < 196) bsums[t] = sh[t] - v;           // exclusive
}

__global__ void k_scan3(int* rowptr, const int* __restrict__ bsums) {
    int i = blockIdx.x * 256 + threadIdx.x;
    if (i < N_NODES) rowptr[i] += bsums[blockIdx.x];
    if (i == 0) rowptr[N_NODES] = ET;
}

__global__ void k_scatter(const int* __restrict__ eidx, const int* __restrict__ rowptr,
                          int* cursor, int* esrc) {
    int e = blockIdx.x * 256 + threadIdx.x;
    if (e >= ET) return;
    int s, d;
    if (e < N_EDGE) { s = eidx[e]; d = eidx[N_EDGE + e]; }
    else            { s = e - N_EDGE; d = s; }
    int pos = rowptr[d] + atomicAdd(&cursor[d], 1);
    esrc[pos] = s;
}

// ---------------- prep: W1 -> bf16 transposed [n][k] ----------------
__global__ void k_prepW1(const float* __restrict__ W1, ushort* __restrict__ W1T) {
    int i = blockIdx.x * 256 + threadIdx.x;      // i = n*256 + k
    if (i >= F1 * IN_DIM) return;
    int n = i >> 8, k = i & 255;
    W1T[i] = f2b(W1[k * F1 + n]);
}

// ---------------- layer 1 GEMM via MFMA (+ fused attention logits) ----------------
// block: 256 thr = 4 waves; tile 64 rows x 128 cols; wave w -> rows w*16..+15
__global__ __launch_bounds__(256) void k_gemm1m(
        const float* __restrict__ x, const ushort* __restrict__ W1T,
        const float* __restrict__ a_src1, const float* __restrict__ a_dst1,
        ushort* __restrict__ h1b, float* __restrict__ als1, float* __restrict__ ald1) {
    __shared__ ushort As[64 * 40];   // [row][k], pad 32->40 to break bank stride
    __shared__ ushort Bs[128 * 40];  // [n][k]
    int t = threadIdx.x;
    int w = t >> 6, lane = t & 63;
    int cl = lane & 15, q = lane >> 4;
    int r0 = blockIdx.x * 64;

    f32x4 acc[8];
#pragma unroll
    for (int i = 0; i < 8; i++) acc[i] = (f32x4){0.f, 0.f, 0.f, 0.f};

    int arow = t >> 2;               // A staging: row, 8 consecutive k
    int akp  = (t & 3) * 8;
    int brow = t >> 1;               // B staging: n, 16 consecutive k
    int bkp  = (t & 1) * 16;
    int agr  = r0 + arow;

    for (int kc = 0; kc < IN_DIM; kc += 32) {
        float4 f0, f1;
        if (agr < N_NODES) {
            f0 = *(const float4*)&x[(size_t)agr * IN_DIM + kc + akp];
            f1 = *(const float4*)&x[(size_t)agr * IN_DIM + kc + akp + 4];
        } else {
            f0 = make_float4(0.f, 0.f, 0.f, 0.f);
            f1 = f0;
        }
        ushort4 u0 = {f2b(f0.x), f2b(f0.y), f2b(f0.z), f2b(f0.w)};
        ushort4 u1 = {f2b(f1.x), f2b(f1.y), f2b(f1.z), f2b(f1.w)};
        *(ushort4*)&As[arow * 40 + akp]     = u0;
        *(ushort4*)&As[arow * 40 + akp + 4] = u1;

        *(uint4*)&Bs[brow * 40 + bkp]     = *(const uint4*)&W1T[brow * IN_DIM + kc + bkp];
        *(uint4*)&Bs[brow * 40 + bkp + 8] = *(const uint4*)&W1T[brow * IN_DIM + kc + bkp + 8];
        __syncthreads();

        bf16_8 af = *(bf16_8*)&As[(w * 16 + cl) * 40 + q * 8];
#pragma unroll
        for (int ct = 0; ct < 8; ct++) {
            bf16_8 bfr = *(bf16_8*)&Bs[(ct * 16 + cl) * 40 + q * 8];
            acc[ct] = __builtin_amdgcn_mfma_f32_16x16x32_bf16(af, bfr, acc[ct], 0, 0, 0);
        }
        __syncthreads();
    }

    float asv[8], adv[8];
#pragma unroll
    for (int ct = 0; ct < 8; ct++) {
        asv[ct] = a_src1[ct * 16 + cl];
        adv[ct] = a_dst1[ct * 16 + cl];
    }

#pragma unroll
    for (int reg = 0; reg < 4; reg++) {
        int grow = r0 + w * 16 + q * 4 + reg;
        bool ok = grow < N_NODES;
        float ps[4] = {0.f, 0.f, 0.f, 0.f};
        float pd[4] = {0.f, 0.f, 0.f, 0.f};
#pragma unroll
        for (int ct = 0; ct < 8; ct++) {
            float v = acc[ct][reg];
            if (ok) h1b[(size_t)grow * F1 + ct * 16 + cl] = f2b(v);
            ps[ct >> 1] += v * asv[ct];
            pd[ct >> 1] += v * adv[ct];
        }
#pragma unroll
        for (int hh = 0; hh < 4; hh++) {
            ps[hh] += __shfl_xor(ps[hh], 1); ps[hh] += __shfl_xor(ps[hh], 2);
            ps[hh] += __shfl_xor(ps[hh], 4); ps[hh] += __shfl_xor(ps[hh], 8);
            pd[hh] += __shfl_xor(pd[hh], 1); pd[hh] += __shfl_xor(pd[hh], 2);
            pd[hh] += __shfl_xor(pd[hh], 4); pd[hh] += __shfl_xor(pd[hh], 8);
        }
        if (cl == 0 && ok) {
#pragma unroll
            for (int hh = 0; hh < 4; hh++) {
                als1[grow * NHEAD + hh] = ps[hh];
                ald1[grow * NHEAD + hh] = pd[hh];
            }
        }
    }
}

// ---------------- layer 1: fused softmax + aggregation + bias + ELU ----------------
// block of 128 threads per dst node; col = t, head = t>>5
__global__ __launch_bounds__(128) void k_agg1f(
        const int* __restrict__ rowptr, const int* __restrict__ esrc,
        const float* __restrict__ als1, const float* __restrict__ ald1,
        const ushort* __restrict__ h1b, const float* __restrict__ b1,
        ushort* __restrict__ h1outb) {
    __shared__ int   s_src[64];
    __shared__ float s_p[64][4];
    __shared__ float s_red[8];
    int n = blockIdx.x;
    int t = threadIdx.x;
    int b = rowptr[n], e = rowptr[n + 1];
    int h = t >> 5;
    float4 ad = *(const float4*)&ald1[n * 4];

    // phase 1: per-head max of leaky_relu(als_src + ald_dst)
    float m0 = -1e30f, m1 = -1e30f, m2 = -1e30f, m3 = -1e30f;
    for (int j = b + t; j < e; j += 128) {
        float4 as = *(const float4*)&als1[esrc[j] * 4];
        m0 = fmaxf(m0, lrelu(as.x + ad.x));
        m1 = fmaxf(m1, lrelu(as.y + ad.y));
        m2 = fmaxf(m2, lrelu(as.z + ad.z));
        m3 = fmaxf(m3, lrelu(as.w + ad.w));
    }
#pragma unroll
    for (int off = 1; off < 64; off <<= 1) {
        m0 = fmaxf(m0, __shfl_xor(m0, off));
        m1 = fmaxf(m1, __shfl_xor(m1, off));
        m2 = fmaxf(m2, __shfl_xor(m2, off));
        m3 = fmaxf(m3, __shfl_xor(m3, off));
    }
    if ((t & 63) == 0) {
        int w = t >> 6;
        s_red[w * 4 + 0] = m0; s_red[w * 4 + 1] = m1;
        s_red[w * 4 + 2] = m2; s_red[w * 4 + 3] = m3;
    }
    __syncthreads();
    m0 = fmaxf(s_red[0], s_red[4]); m1 = fmaxf(s_red[1], s_red[5]);
    m2 = fmaxf(s_red[2], s_red[6]); m3 = fmaxf(s_red[3], s_red[7]);
    __syncthreads();

    // phase 2: per-chunk p into LDS + aggregation
    float ss0 = 0.f, ss1v = 0.f, ss2v = 0.f, ss3v = 0.f;   // wave-0 partials
    float acc = 0.f;
    for (int base = b; base < e; base += 64) {
        int cnt = min(64, e - base);
        if (t < cnt) {
            int s = esrc[base + t];
            s_src[t] = s;
            float4 as = *(const float4*)&als1[s * 4];
            float p0 = __expf(lrelu(as.x + ad.x) - m0);
            float p1 = __expf(lrelu(as.y + ad.y) - m1);
            float p2 = __expf(lrelu(as.z + ad.z) - m2);
            float p3 = __expf(lrelu(as.w + ad.w) - m3);
            s_p[t][0] = p0; s_p[t][1] = p1; s_p[t][2] = p2; s_p[t][3] = p3;
            ss0 += p0; ss1v += p1; ss2v += p2; ss3v += p3;
        }
        __syncthreads();
        for (int j = 0; j < cnt; j++)
            acc += s_p[j][h] * b2f(h1b[(size_t)s_src[j] * F1 + t]);
        __syncthreads();
    }

    // reduce expsum over wave 0 (staging threads are all in wave 0)
    if (t < 64) {
#pragma unroll
        for (int off = 1; off < 64; off <<= 1) {
            ss0  += __shfl_xor(ss0, off);
            ss1v += __shfl_xor(ss1v, off);
            ss2v += __shfl_xor(ss2v, off);
            ss3v += __shfl_xor(ss3v, off);
        }
        if (t == 0) { s_red[0] = ss0; s_red[1] = ss1v; s_red[2] = ss2v; s_red[3] = ss3v; }
    }
    __syncthreads();
    float v = acc / s_red[h] + b1[t];
    v = (v > 0.f) ? v : (__expf(v) - 1.f);      // ELU
    h1outb[(size_t)n * F1 + t] = f2b(v);
}

// ---------------- layer 2 GEMM (+ fused logits) ----------------
__global__ __launch_bounds__(256) void k_gemm2(
        const ushort* __restrict__ h1outb, const float* __restrict__ W2,
        const float* __restrict__ a_src2, const float* __restrict__ a_dst2,
        ushort* __restrict__ h2b, float* __restrict__ als2, float* __restrict__ ald2) {
    __shared__ float hs[64][129];
    __shared__ float w2s[128][40];
    int t = threadIdx.x;
    int r0 = blockIdx.x * 64;
    for (int i = t; i < F1 * OUT_C; i += 256) w2s[i / 40][i % 40] = W2[i];
    for (int i = t; i < 64 * F1; i += 256) {
        int row = i >> 7, col = i & 127;
        int gr = r0 + row;
        hs[row][col] = (gr < N_NODES) ? b2f(h1outb[(size_t)gr * F1 + col]) : 0.f;
    }
    __syncthreads();
    int row = t >> 2;
    int cb  = (t & 3) * 10;
    float acc[10] = {};
    for (int k = 0; k < F1; k++) {
        float a = hs[row][k];
#pragma unroll
        for (int i = 0; i < 10; i++) acc[i] += a * w2s[k][cb + i];
    }
    int gr = r0 + row;
    float ps = 0.f, pd = 0.f;
#pragma unroll
    for (int i = 0; i < 10; i++) {
        ps += acc[i] * a_src2[cb + i];
        pd += acc[i] * a_dst2[cb + i];
    }
    ps += __shfl_xor(ps, 1); ps += __shfl_xor(ps, 2);
    pd += __shfl_xor(pd, 1); pd += __shfl_xor(pd, 2);
    if ((t & 3) == 0 && gr < N_NODES) { als2[gr] = ps; ald2[gr] = pd; }
    if (gr < N_NODES) {
#pragma unroll
        for (int i = 0; i < 10; i++) h2b[(size_t)gr * OUT_C + cb + i] = f2b(acc[i]);
    }
}

// ---------------- layer 2: fused softmax + aggregation + bias + log_softmax ----------------
__global__ __launch_bounds__(256) void k_agg2f(
        const int* __restrict__ rowptr, const int* __restrict__ esrc,
        const float* __restrict__ als2, const float* __restrict__ ald2,
        const ushort* __restrict__ h2b, const float* __restrict__ b2,
        float* __restrict__ out) {
    int wv = threadIdx.x >> 6;
    int ln = threadIdx.x & 63;
    int n = blockIdx.x * 4 + wv;
    if (n >= N_NODES) return;
    int b = rowptr[n], e = rowptr[n + 1];
    float ad = ald2[n];

    // pass 1: max
    float m = -1e30f;
    for (int j = b + ln; j < e; j += 64)
        m = fmaxf(m, lrelu(als2[esrc[j]] + ad));
#pragma unroll
    for (int off = 1; off < 64; off <<= 1) m = fmaxf(m, __shfl_xor(m, off));

    // pass 2: exp + aggregate
    float acc = 0.f, ss = 0.f;
    for (int base = b; base < e; base += 64) {
        int cnt = min(64, e - base);
        int s_reg = 0; float p_reg = 0.f;
        if (ln < cnt) {
            s_reg = esrc[base + ln];
            p_reg = __expf(lrelu(als2[s_reg] + ad) - m);
            ss += p_reg;
        }
        for (int j = 0; j < cnt; j++) {
            int   s = __shfl(s_reg, j);
            float p = __shfl(p_reg, j);
            if (ln < OUT_C) acc += p * b2f(h2b[(size_t)s * OUT_C + ln]);
        }
    }
#pragma unroll
    for (int off = 1; off < 64; off <<= 1) ss += __shfl_xor(ss, off);

    float y = (ln < OUT_C) ? acc / ss + b2[ln] : -1e30f;
    float mx = y;
#pragma unroll
    for (int off = 1; off < 64; off <<= 1) mx = fmaxf(mx, __shfl_xor(mx, off));
    float z = (ln < OUT_C) ? __expf(y - mx) : 0.f;
    float sm = z;
#pragma unroll
    for (int off = 1; off < 64; off <<= 1) sm += __shfl_xor(sm, off);
    if (ln < OUT_C) out[(size_t)n * OUT_C + ln] = y - mx - logf(sm);
}

extern "C" void kernel_launch(void* const* d_in, const int* in_sizes, int n_in,
                              void* d_out, int out_size, void* d_ws, size_t ws_size,
                              hipStream_t stream) {
    const float* x      = (const float*)d_in[0];
    const int*   eidx   = (const int*)d_in[1];
    const float* W1     = (const float*)d_in[2];
    const float* a_src1 = (const float*)d_in[3];
    const float* a_dst1 = (const float*)d_in[4];
    const float* b1     = (const float*)d_in[5];
    const float* W2     = (const float*)d_in[6];
    const float* a_src2 = (const float*)d_in[7];
    const float* a_dst2 = (const float*)d_in[8];
    const float* b2     = (const float*)d_in[9];
    float* out = (float*)d_out;

    // workspace layout
    float* wf    = (float*)d_ws;
    float* als1  = wf;                   // 200,000
    float* ald1  = wf + 200000;          // 200,000
    float* als2  = wf + 400000;          // 50,000
    float* ald2  = wf + 450000;          // 50,000
    ushort* h1b    = (ushort*)(wf + 500000);   // 6,400,000 ushorts
    ushort* h1outb = h1b + 6400000;            // 6,400,000
    ushort* h2b    = h1outb + 6400000;         // 2,000,000
    ushort* W1T    = h2b + 2000000;            // 32,768
    int* ip      = (int*)(W1T + 32768);
    int* rowptr  = ip;                   // 50,001
    int* cnt     = ip + 50001;           // 50,000
    int* cursor  = ip + 100001;          // 50,000
    int* esrc    = ip + 150001;          // 850,000
    int* bsums   = ip + 1000001;         // 256

    // graph build
    k_init   <<<196, 256, 0, stream>>>(cnt, cursor);
    k_deg    <<<(N_EDGE + 255) / 256, 256, 0, stream>>>(eidx, cnt);
    k_scan1  <<<196, 256, 0, stream>>>(cnt, rowptr, bsums);
    k_scan2  <<<1, 256, 0, stream>>>(bsums);
    k_scan3  <<<196, 256, 0, stream>>>(rowptr, bsums);
    k_scatter<<<(ET + 255) / 256, 256, 0, stream>>>(eidx, rowptr, cursor, esrc);

    // layer 1
    k_prepW1<<<(F1 * IN_DIM + 255) / 256, 256, 0, stream>>>(W1, W1T);
    k_gemm1m<<<(N_NODES + 63) / 64, 256, 0, stream>>>(x, W1T, a_src1, a_dst1, h1b, als1, ald1);
    k_agg1f<<<N_NODES, 128, 0, stream>>>(rowptr, esrc, als1, ald1, h1b, b1, h1outb);

    // layer 2
    k_gemm2<<<(N_NODES + 63) / 64, 256, 0, stream>>>(h1outb, W2, a_src2, a_dst2, h2b, als2, ald2);
    k_agg2f<<<(N_NODES + 3) / 4, 256, 0, stream>>>(rowptr, esrc, als2, ald2, h2b, b2, out);
}

// Round 4
// 367.494 us; speedup vs baseline: 1.2672x; 1.0318x over previous
//
#include <hip/hip_runtime.h>
#include <hip/hip_bf16.h>

#define N_NODES 50000
#define N_EDGE  800000
#define ET      850000          // N_EDGE + N_NODES self loops
#define IN_DIM  256
#define F1      128             // H1*C1
#define NHEAD   4
#define C1      32
#define OUT_C   40
#define NEG     0.2f

typedef __bf16 bf16_8 __attribute__((ext_vector_type(8)));
typedef float  f32x4  __attribute__((ext_vector_type(4)));

static __device__ __forceinline__ ushort f2b(float f) {
    __hip_bfloat16 h = __float2bfloat16(f);
    return *reinterpret_cast<ushort*>(&h);
}
static __device__ __forceinline__ float b2f(ushort u) {
    unsigned v = ((unsigned)u) << 16;
    return __uint_as_float(v);
}
static __device__ __forceinline__ float lrelu(float v) {
    return (v > 0.f) ? v : NEG * v;
}

// ---------------- graph build ----------------
__global__ void k_init(int* cnt, int* cursor) {
    int i = blockIdx.x * 256 + threadIdx.x;
    if (i < N_NODES) { cnt[i] = 1; cursor[i] = 0; }   // 1 = self loop
}

__global__ void k_deg(const int* __restrict__ eidx, int* cnt) {
    int e = blockIdx.x * 256 + threadIdx.x;
    if (e < N_EDGE) atomicAdd(&cnt[eidx[N_EDGE + e]], 1);
}

__global__ void k_scan1(const int* __restrict__ cnt, int* rowptr, int* bsums) {
    __shared__ int sh[256];
    int t = threadIdx.x;
    int i = blockIdx.x * 256 + t;
    int v = (i < N_NODES) ? cnt[i] : 0;
    sh[t] = v; __syncthreads();
    for (int off = 1; off < 256; off <<= 1) {
        int x = (t >= off) ? sh[t - off] : 0;
        __syncthreads();
        sh[t] += x;
        __syncthreads();
    }
    if (i < N_NODES) rowptr[i] = sh[t] - v;      // exclusive
    if (t == 255) bsums[blockIdx.x] = sh[t];     // block total
}

__global__ void k_scan2(int* bsums) {
    __shared__ int sh[256];
    int t = threadIdx.x;
    int v = (t < 196) ? bsums[t] : 0;
    sh[t] = v; __syncthreads();
    for (int off = 1; off < 256; off <<= 1) {
        int x = (t >= off) ? sh[t - off] : 0;
        __syncthreads();
        sh[t] += x;
        __syncthreads();
    }
    if (t < 196) bsums[t] = sh[t] - v;           // exclusive
}

__global__ void k_scan3(int* rowptr, const int* __restrict__ bsums) {
    int i = blockIdx.x * 256 + threadIdx.x;
    if (i < N_NODES) rowptr[i] += bsums[blockIdx.x];
    if (i == 0) rowptr[N_NODES] = ET;
}

__global__ void k_scatter(const int* __restrict__ eidx, const int* __restrict__ rowptr,
                          int* cursor, int* esrc) {
    int e = blockIdx.x * 256 + threadIdx.x;
    if (e >= ET) return;
    int s, d;
    if (e < N_EDGE) { s = eidx[e]; d = eidx[N_EDGE + e]; }
    else            { s = e - N_EDGE; d = s; }
    int pos = rowptr[d] + atomicAdd(&cursor[d], 1);
    esrc[pos] = s;
}

// ---------------- prep: W1 -> bf16 transposed [n][k] ----------------
__global__ void k_prepW1(const float* __restrict__ W1, ushort* __restrict__ W1T) {
    int i = blockIdx.x * 256 + threadIdx.x;      // i = n*256 + k
    if (i >= F1 * IN_DIM) return;
    int n = i >> 8, k = i & 255;
    W1T[i] = f2b(W1[k * F1 + n]);
}

// ---------------- layer 1 GEMM via MFMA (+ fused attention logits) ----------------
// block: 256 thr = 4 waves; tile 64 rows x 128 cols; wave w -> rows w*16..+15
__global__ __launch_bounds__(256) void k_gemm1m(
        const float* __restrict__ x, const ushort* __restrict__ W1T,
        const float* __restrict__ a_src1, const float* __restrict__ a_dst1,
        ushort* __restrict__ h1b, float* __restrict__ als1, float* __restrict__ ald1) {
    __shared__ ushort As[64 * 40];   // [row][k], pad 32->40 to break bank stride
    __shared__ ushort Bs[128 * 40];  // [n][k]
    int t = threadIdx.x;
    int w = t >> 6, lane = t & 63;
    int cl = lane & 15, q = lane >> 4;
    int r0 = blockIdx.x * 64;

    f32x4 acc[8];
#pragma unroll
    for (int i = 0; i < 8; i++) acc[i] = (f32x4){0.f, 0.f, 0.f, 0.f};

    int arow = t >> 2;               // A staging: row, 8 consecutive k
    int akp  = (t & 3) * 8;
    int brow = t >> 1;               // B staging: n, 16 consecutive k
    int bkp  = (t & 1) * 16;
    int agr  = r0 + arow;

    for (int kc = 0; kc < IN_DIM; kc += 32) {
        float4 f0, f1;
        if (agr < N_NODES) {
            f0 = *(const float4*)&x[(size_t)agr * IN_DIM + kc + akp];
            f1 = *(const float4*)&x[(size_t)agr * IN_DIM + kc + akp + 4];
        } else {
            f0 = make_float4(0.f, 0.f, 0.f, 0.f);
            f1 = f0;
        }
        ushort4 u0 = {f2b(f0.x), f2b(f0.y), f2b(f0.z), f2b(f0.w)};
        ushort4 u1 = {f2b(f1.x), f2b(f1.y), f2b(f1.z), f2b(f1.w)};
        *(ushort4*)&As[arow * 40 + akp]     = u0;
        *(ushort4*)&As[arow * 40 + akp + 4] = u1;

        *(uint4*)&Bs[brow * 40 + bkp]     = *(const uint4*)&W1T[brow * IN_DIM + kc + bkp];
        *(uint4*)&Bs[brow * 40 + bkp + 8] = *(const uint4*)&W1T[brow * IN_DIM + kc + bkp + 8];
        __syncthreads();

        bf16_8 af = *(bf16_8*)&As[(w * 16 + cl) * 40 + q * 8];
#pragma unroll
        for (int ct = 0; ct < 8; ct++) {
            bf16_8 bfr = *(bf16_8*)&Bs[(ct * 16 + cl) * 40 + q * 8];
            acc[ct] = __builtin_amdgcn_mfma_f32_16x16x32_bf16(af, bfr, acc[ct], 0, 0, 0);
        }
        __syncthreads();
    }

    float asv[8], adv[8];
#pragma unroll
    for (int ct = 0; ct < 8; ct++) {
        asv[ct] = a_src1[ct * 16 + cl];
        adv[ct] = a_dst1[ct * 16 + cl];
    }

#pragma unroll
    for (int reg = 0; reg < 4; reg++) {
        int grow = r0 + w * 16 + q * 4 + reg;
        bool ok = grow < N_NODES;
        float ps[4] = {0.f, 0.f, 0.f, 0.f};
        float pd[4] = {0.f, 0.f, 0.f, 0.f};
#pragma unroll
        for (int ct = 0; ct < 8; ct++) {
            float v = acc[ct][reg];
            if (ok) h1b[(size_t)grow * F1 + ct * 16 + cl] = f2b(v);
            ps[ct >> 1] += v * asv[ct];
            pd[ct >> 1] += v * adv[ct];
        }
#pragma unroll
        for (int hh = 0; hh < 4; hh++) {
            ps[hh] += __shfl_xor(ps[hh], 1); ps[hh] += __shfl_xor(ps[hh], 2);
            ps[hh] += __shfl_xor(ps[hh], 4); ps[hh] += __shfl_xor(ps[hh], 8);
            pd[hh] += __shfl_xor(pd[hh], 1); pd[hh] += __shfl_xor(pd[hh], 2);
            pd[hh] += __shfl_xor(pd[hh], 4); pd[hh] += __shfl_xor(pd[hh], 8);
        }
        if (cl == 0 && ok) {
#pragma unroll
            for (int hh = 0; hh < 4; hh++) {
                als1[grow * NHEAD + hh] = ps[hh];
                ald1[grow * NHEAD + hh] = pd[hh];
            }
        }
    }
}

// ---------------- layer 1: fused online-softmax aggregation, one wave per node ----------------
// lane l: cols 2l,2l+1 (head = l>>4); chunk of 16 edges: lane computes p for
// (edge l&15, head l>>4); p broadcast via shfl from lane (l&48)+j. No LDS, no barriers.
__global__ __launch_bounds__(256) void k_agg1w(
        const int* __restrict__ rowptr, const int* __restrict__ esrc,
        const float* __restrict__ als1, const float* __restrict__ ald1,
        const uint* __restrict__ h1u, const float* __restrict__ b1,
        uint* __restrict__ h1outu) {
    int w = threadIdx.x >> 6, ln = threadIdx.x & 63;
    int n = blockIdx.x * 4 + w;
    if (n >= N_NODES) return;
    int b = rowptr[n], e = rowptr[n + 1];
    int h  = ln >> 4;           // head for this lane
    int el = ln & 15;           // edge slot within chunk
    int srcbase = ln & 48;      // lane holding (h, edge j) is srcbase + j
    float ad = ald1[n * 4 + h];

    float acc0 = 0.f, acc1 = 0.f, ssum = 0.f;
    float m = -1e30f;

    for (int base = b; base < e; base += 16) {
        int cnt = min(16, e - base);
        int s_reg = esrc[base + (el < cnt ? el : 0)];
        float v = lrelu(als1[s_reg * 4 + h] + ad);
        if (el >= cnt) v = -1e30f;
        // per-head chunk max (16-lane groups)
        float cm = v;
        cm = fmaxf(cm, __shfl_xor(cm, 1));
        cm = fmaxf(cm, __shfl_xor(cm, 2));
        cm = fmaxf(cm, __shfl_xor(cm, 4));
        cm = fmaxf(cm, __shfl_xor(cm, 8));
        float nm = fmaxf(m, cm);
        float sc = __expf(m - nm);          // first chunk: exp(-inf)=0, acc=0 anyway
        acc0 *= sc; acc1 *= sc; ssum *= sc;
        m = nm;
        float p = __expf(v - m);            // inactive slots: exp(-inf)=0
        for (int j = 0; j < cnt; j++) {
            int   s  = __shfl(s_reg, j);
            float pj = __shfl(p, srcbase + j);
            uint hv = h1u[(size_t)s * 64 + ln];
            ssum += pj;
            acc0 = fmaf(pj, __uint_as_float(hv << 16), acc0);
            acc1 = fmaf(pj, __uint_as_float(hv & 0xffff0000u), acc1);
        }
    }

    float inv = 1.f / ssum;
    int c0 = ln * 2;
    float2 bb = *(const float2*)&b1[c0];
    float v0 = acc0 * inv + bb.x;
    float v1 = acc1 * inv + bb.y;
    v0 = (v0 > 0.f) ? v0 : (__expf(v0) - 1.f);   // ELU
    v1 = (v1 > 0.f) ? v1 : (__expf(v1) - 1.f);
    h1outu[(size_t)n * 64 + ln] = (uint)f2b(v0) | ((uint)f2b(v1) << 16);
}

// ---------------- layer 2 GEMM (+ fused logits) ----------------
__global__ __launch_bounds__(256) void k_gemm2(
        const ushort* __restrict__ h1outb, const float* __restrict__ W2,
        const float* __restrict__ a_src2, const float* __restrict__ a_dst2,
        ushort* __restrict__ h2b, float* __restrict__ als2, float* __restrict__ ald2) {
    __shared__ float hs[64][129];
    __shared__ float w2s[128][40];
    int t = threadIdx.x;
    int r0 = blockIdx.x * 64;
    for (int i = t; i < F1 * OUT_C; i += 256) w2s[i / 40][i % 40] = W2[i];
    for (int i = t; i < 64 * F1; i += 256) {
        int row = i >> 7, col = i & 127;
        int gr = r0 + row;
        hs[row][col] = (gr < N_NODES) ? b2f(h1outb[(size_t)gr * F1 + col]) : 0.f;
    }
    __syncthreads();
    int row = t >> 2;
    int cb  = (t & 3) * 10;
    float acc[10] = {};
    for (int k = 0; k < F1; k++) {
        float a = hs[row][k];
#pragma unroll
        for (int i = 0; i < 10; i++) acc[i] += a * w2s[k][cb + i];
    }
    int gr = r0 + row;
    float ps = 0.f, pd = 0.f;
#pragma unroll
    for (int i = 0; i < 10; i++) {
        ps += acc[i] * a_src2[cb + i];
        pd += acc[i] * a_dst2[cb + i];
    }
    ps += __shfl_xor(ps, 1); ps += __shfl_xor(ps, 2);
    pd += __shfl_xor(pd, 1); pd += __shfl_xor(pd, 2);
    if ((t & 3) == 0 && gr < N_NODES) { als2[gr] = ps; ald2[gr] = pd; }
    if (gr < N_NODES) {
#pragma unroll
        for (int i = 0; i < 10; i++) h2b[(size_t)gr * OUT_C + cb + i] = f2b(acc[i]);
    }
}

// ---------------- layer 2: fused online-softmax aggregation + log_softmax ----------------
// one wave per node; lane l<20: cols 2l,2l+1; all 64 lanes stage edges/p.
__global__ __launch_bounds__(256) void k_agg2w(
        const int* __restrict__ rowptr, const int* __restrict__ esrc,
        const float* __restrict__ als2, const float* __restrict__ ald2,
        const uint* __restrict__ h2u, const float* __restrict__ b2,
        float* __restrict__ out) {
    int w = threadIdx.x >> 6, ln = threadIdx.x & 63;
    int n = blockIdx.x * 4 + w;
    if (n >= N_NODES) return;
    int b = rowptr[n], e = rowptr[n + 1];
    float ad = ald2[n];

    float acc0 = 0.f, acc1 = 0.f, ssum = 0.f;
    float m = -1e30f;
    for (int base = b; base < e; base += 64) {
        int cnt = min(64, e - base);
        int s_reg = esrc[base + (ln < cnt ? ln : 0)];
        float v = lrelu(als2[s_reg] + ad);
        if (ln >= cnt) v = -1e30f;
        float cm = v;
#pragma unroll
        for (int off = 1; off < 64; off <<= 1) cm = fmaxf(cm, __shfl_xor(cm, off));
        float nm = fmaxf(m, cm);
        float sc = __expf(m - nm);
        acc0 *= sc; acc1 *= sc; ssum *= sc;
        m = nm;
        float p = __expf(v - m);
        for (int j = 0; j < cnt; j++) {
            int   s  = __shfl(s_reg, j);
            float pj = __shfl(p, j);
            ssum += pj;
            if (ln < 20) {
                uint hv = h2u[(size_t)s * 20 + ln];
                acc0 = fmaf(pj, __uint_as_float(hv << 16), acc0);
                acc1 = fmaf(pj, __uint_as_float(hv & 0xffff0000u), acc1);
            }
        }
    }
    float inv = 1.f / ssum;
    int c0 = ln * 2;
    float y0 = -1e30f, y1 = -1e30f;
    if (ln < 20) {
        y0 = acc0 * inv + b2[c0];
        y1 = acc1 * inv + b2[c0 + 1];
    }
    float mx = fmaxf(y0, y1);
#pragma unroll
    for (int off = 1; off < 64; off <<= 1) mx = fmaxf(mx, __shfl_xor(mx, off));
    float z = (ln < 20) ? (__expf(y0 - mx) + __expf(y1 - mx)) : 0.f;
#pragma unroll
    for (int off = 1; off < 64; off <<= 1) z += __shfl_xor(z, off);
    float lg = logf(z);
    if (ln < 20) {
        float2 o = make_float2(y0 - mx - lg, y1 - mx - lg);
        *(float2*)&out[(size_t)n * OUT_C + c0] = o;
    }
}

extern "C" void kernel_launch(void* const* d_in, const int* in_sizes, int n_in,
                              void* d_out, int out_size, void* d_ws, size_t ws_size,
                              hipStream_t stream) {
    const float* x      = (const float*)d_in[0];
    const int*   eidx   = (const int*)d_in[1];
    const float* W1     = (const float*)d_in[2];
    const float* a_src1 = (const float*)d_in[3];
    const float* a_dst1 = (const float*)d_in[4];
    const float* b1     = (const float*)d_in[5];
    const float* W2     = (const float*)d_in[6];
    const float* a_src2 = (const float*)d_in[7];
    const float* a_dst2 = (const float*)d_in[8];
    const float* b2     = (const float*)d_in[9];
    float* out = (float*)d_out;

    // workspace layout
    float* wf    = (float*)d_ws;
    float* als1  = wf;                   // 200,000
    float* ald1  = wf + 200000;          // 200,000
    float* als2  = wf + 400000;          // 50,000
    float* ald2  = wf + 450000;          // 50,000
    ushort* h1b    = (ushort*)(wf + 500000);   // 6,400,000 ushorts
    ushort* h1outb = h1b + 6400000;            // 6,400,000
    ushort* h2b    = h1outb + 6400000;         // 2,000,000
    ushort* W1T    = h2b + 2000000;            // 32,768
    int* ip      = (int*)(W1T + 32768);
    int* rowptr  = ip;                   // 50,001
    int* cnt     = ip + 50001;           // 50,000
    int* cursor  = ip + 100001;          // 50,000
    int* esrc    = ip + 150001;          // 850,000
    int* bsums   = ip + 1000001;         // 256

    // graph build
    k_init   <<<196, 256, 0, stream>>>(cnt, cursor);
    k_deg    <<<(N_EDGE + 255) / 256, 256, 0, stream>>>(eidx, cnt);
    k_scan1  <<<196, 256, 0, stream>>>(cnt, rowptr, bsums);
    k_scan2  <<<1, 256, 0, stream>>>(bsums);
    k_scan3  <<<196, 256, 0, stream>>>(rowptr, bsums);
    k_scatter<<<(ET + 255) / 256, 256, 0, stream>>>(eidx, rowptr, cursor, esrc);

    // layer 1
    k_prepW1<<<(F1 * IN_DIM + 255) / 256, 256, 0, stream>>>(W1, W1T);
    k_gemm1m<<<(N_NODES + 63) / 64, 256, 0, stream>>>(x, W1T, a_src1, a_dst1, h1b, als1, ald1);
    k_agg1w<<<(N_NODES + 3) / 4, 256, 0, stream>>>(rowptr, esrc, als1, ald1,
                                                   (const uint*)h1b, b1, (uint*)h1outb);

    // layer 2
    k_gemm2<<<(N_NODES + 63) / 64, 256, 0, stream>>>(h1outb, W2, a_src2, a_dst2, h2b, als2, ald2);
    k_agg2w<<<(N_NODES + 3) / 4, 256, 0, stream>>>(rowptr, esrc, als2, ald2,
                                                   (const uint*)h2b, b2, out);
}

// Round 5
// 347.740 us; speedup vs baseline: 1.3392x; 1.0568x over previous
//
#include <hip/hip_runtime.h>
#include <hip/hip_bf16.h>

#define N_NODES 50000
#define N_EDGE  800000
#define ET      850000          // N_EDGE + N_NODES self loops
#define IN_DIM  256
#define F1      128             // H1*C1
#define NHEAD   4
#define C1      32
#define OUT_C   40
#define NEG     0.2f

typedef __bf16 bf16_8 __attribute__((ext_vector_type(8)));
typedef float  f32x4  __attribute__((ext_vector_type(4)));

static __device__ __forceinline__ ushort f2b(float f) {
    __hip_bfloat16 h = __float2bfloat16(f);
    return *reinterpret_cast<ushort*>(&h);
}
static __device__ __forceinline__ float b2f(ushort u) {
    unsigned v = ((unsigned)u) << 16;
    return __uint_as_float(v);
}
static __device__ __forceinline__ float lrelu(float v) {
    return (v > 0.f) ? v : NEG * v;
}

// ---------------- graph build ----------------
__global__ void k_init(int* cnt, int* cursor) {
    int i = blockIdx.x * 256 + threadIdx.x;
    if (i < N_NODES) { cnt[i] = 1; cursor[i] = 0; }   // 1 = self loop
}

__global__ void k_deg(const int* __restrict__ eidx, int* cnt) {
    int e = blockIdx.x * 256 + threadIdx.x;
    if (e < N_EDGE) atomicAdd(&cnt[eidx[N_EDGE + e]], 1);
}

__global__ void k_scan1(const int* __restrict__ cnt, int* rowptr, int* bsums) {
    __shared__ int sh[256];
    int t = threadIdx.x;
    int i = blockIdx.x * 256 + t;
    int v = (i < N_NODES) ? cnt[i] : 0;
    sh[t] = v; __syncthreads();
    for (int off = 1; off < 256; off <<= 1) {
        int x = (t >= off) ? sh[t - off] : 0;
        __syncthreads();
        sh[t] += x;
        __syncthreads();
    }
    if (i < N_NODES) rowptr[i] = sh[t] - v;      // exclusive
    if (t == 255) bsums[blockIdx.x] = sh[t];     // block total
}

__global__ void k_scan2(int* bsums) {
    __shared__ int sh[256];
    int t = threadIdx.x;
    int v = (t < 196) ? bsums[t] : 0;
    sh[t] = v; __syncthreads();
    for (int off = 1; off < 256; off <<= 1) {
        int x = (t >= off) ? sh[t - off] : 0;
        __syncthreads();
        sh[t] += x;
        __syncthreads();
    }
    if (t < 196) bsums[t] = sh[t] - v;           // exclusive
}

__global__ void k_scan3(int* rowptr, const int* __restrict__ bsums) {
    int i = blockIdx.x * 256 + threadIdx.x;
    if (i < N_NODES) rowptr[i] += bsums[blockIdx.x];
    if (i == 0) rowptr[N_NODES] = ET;
}

__global__ void k_scatter(const int* __restrict__ eidx, const int* __restrict__ rowptr,
                          int* cursor, int* esrc) {
    int e = blockIdx.x * 256 + threadIdx.x;
    if (e >= ET) return;
    int s, d;
    if (e < N_EDGE) { s = eidx[e]; d = eidx[N_EDGE + e]; }
    else            { s = e - N_EDGE; d = s; }
    int pos = rowptr[d] + atomicAdd(&cursor[d], 1);
    esrc[pos] = s;
}

// ---------------- prep: W1 -> bf16 transposed [n][k] ----------------
__global__ void k_prepW1(const float* __restrict__ W1, ushort* __restrict__ W1T) {
    int i = blockIdx.x * 256 + threadIdx.x;      // i = n*256 + k
    if (i >= F1 * IN_DIM) return;
    int n = i >> 8, k = i & 255;
    W1T[i] = f2b(W1[k * F1 + n]);
}

// ---------------- layer 1 GEMM via MFMA (+ fused attention logits) ----------------
__global__ __launch_bounds__(256) void k_gemm1m(
        const float* __restrict__ x, const ushort* __restrict__ W1T,
        const float* __restrict__ a_src1, const float* __restrict__ a_dst1,
        ushort* __restrict__ h1b, float* __restrict__ als1, float* __restrict__ ald1) {
    __shared__ ushort As[64 * 40];   // [row][k], pad 32->40 to break bank stride
    __shared__ ushort Bs[128 * 40];  // [n][k]
    int t = threadIdx.x;
    int w = t >> 6, lane = t & 63;
    int cl = lane & 15, q = lane >> 4;
    int r0 = blockIdx.x * 64;

    f32x4 acc[8];
#pragma unroll
    for (int i = 0; i < 8; i++) acc[i] = (f32x4){0.f, 0.f, 0.f, 0.f};

    int arow = t >> 2;               // A staging: row, 8 consecutive k
    int akp  = (t & 3) * 8;
    int brow = t >> 1;               // B staging: n, 16 consecutive k
    int bkp  = (t & 1) * 16;
    int agr  = r0 + arow;

    for (int kc = 0; kc < IN_DIM; kc += 32) {
        float4 f0, f1;
        if (agr < N_NODES) {
            f0 = *(const float4*)&x[(size_t)agr * IN_DIM + kc + akp];
            f1 = *(const float4*)&x[(size_t)agr * IN_DIM + kc + akp + 4];
        } else {
            f0 = make_float4(0.f, 0.f, 0.f, 0.f);
            f1 = f0;
        }
        ushort4 u0 = {f2b(f0.x), f2b(f0.y), f2b(f0.z), f2b(f0.w)};
        ushort4 u1 = {f2b(f1.x), f2b(f1.y), f2b(f1.z), f2b(f1.w)};
        *(ushort4*)&As[arow * 40 + akp]     = u0;
        *(ushort4*)&As[arow * 40 + akp + 4] = u1;

        *(uint4*)&Bs[brow * 40 + bkp]     = *(const uint4*)&W1T[brow * IN_DIM + kc + bkp];
        *(uint4*)&Bs[brow * 40 + bkp + 8] = *(const uint4*)&W1T[brow * IN_DIM + kc + bkp + 8];
        __syncthreads();

        bf16_8 af = *(bf16_8*)&As[(w * 16 + cl) * 40 + q * 8];
#pragma unroll
        for (int ct = 0; ct < 8; ct++) {
            bf16_8 bfr = *(bf16_8*)&Bs[(ct * 16 + cl) * 40 + q * 8];
            acc[ct] = __builtin_amdgcn_mfma_f32_16x16x32_bf16(af, bfr, acc[ct], 0, 0, 0);
        }
        __syncthreads();
    }

    float asv[8], adv[8];
#pragma unroll
    for (int ct = 0; ct < 8; ct++) {
        asv[ct] = a_src1[ct * 16 + cl];
        adv[ct] = a_dst1[ct * 16 + cl];
    }

#pragma unroll
    for (int reg = 0; reg < 4; reg++) {
        int grow = r0 + w * 16 + q * 4 + reg;
        bool ok = grow < N_NODES;
        float ps[4] = {0.f, 0.f, 0.f, 0.f};
        float pd[4] = {0.f, 0.f, 0.f, 0.f};
#pragma unroll
        for (int ct = 0; ct < 8; ct++) {
            float v = acc[ct][reg];
            if (ok) h1b[(size_t)grow * F1 + ct * 16 + cl] = f2b(v);
            ps[ct >> 1] += v * asv[ct];
            pd[ct >> 1] += v * adv[ct];
        }
#pragma unroll
        for (int hh = 0; hh < 4; hh++) {
            ps[hh] += __shfl_xor(ps[hh], 1); ps[hh] += __shfl_xor(ps[hh], 2);
            ps[hh] += __shfl_xor(ps[hh], 4); ps[hh] += __shfl_xor(ps[hh], 8);
            pd[hh] += __shfl_xor(pd[hh], 1); pd[hh] += __shfl_xor(pd[hh], 2);
            pd[hh] += __shfl_xor(pd[hh], 4); pd[hh] += __shfl_xor(pd[hh], 8);
        }
        if (cl == 0 && ok) {
#pragma unroll
            for (int hh = 0; hh < 4; hh++) {
                als1[grow * NHEAD + hh] = ps[hh];
                ald1[grow * NHEAD + hh] = pd[hh];
            }
        }
    }
}

// ---------------- layer 1: fused online-softmax aggregation, one wave per node ----------------
// lane l: cols 2l,2l+1 (head = l>>4). Full 16-edge chunks take the unrolled
// fast path: all 16 row-gathers issued back-to-back (incremental vmcnt waits),
// then the fma chain. Dynamic tail loop for the last partial chunk.
__global__ __launch_bounds__(256) void k_agg1w(
        const int* __restrict__ rowptr, const int* __restrict__ esrc,
        const float* __restrict__ als1, const float* __restrict__ ald1,
        const uint* __restrict__ h1u, const float* __restrict__ b1,
        uint* __restrict__ h1outu) {
    int w = threadIdx.x >> 6, ln = threadIdx.x & 63;
    int n = blockIdx.x * 4 + w;
    if (n >= N_NODES) return;
    int b = rowptr[n], e = rowptr[n + 1];
    int h  = ln >> 4;           // head for this lane
    int el = ln & 15;           // edge slot within chunk
    int srcbase = ln & 48;      // lane holding (h, edge j) is srcbase + j
    float ad = ald1[n * 4 + h];

    float acc0 = 0.f, acc1 = 0.f, ssum = 0.f;
    float m = -1e30f;
    int base = b;

    // fast path: full chunks of 16, loads batched
    for (; base + 16 <= e; base += 16) {
        int s_reg = esrc[base + el];
        float v = lrelu(als1[s_reg * 4 + h] + ad);
        float cm = v;
        cm = fmaxf(cm, __shfl_xor(cm, 1));
        cm = fmaxf(cm, __shfl_xor(cm, 2));
        cm = fmaxf(cm, __shfl_xor(cm, 4));
        cm = fmaxf(cm, __shfl_xor(cm, 8));
        float nm = fmaxf(m, cm);
        float sc = __expf(m - nm);
        acc0 *= sc; acc1 *= sc; ssum *= sc;
        m = nm;
        float p = __expf(v - m);
        uint hv[16];
#pragma unroll
        for (int j = 0; j < 16; j++)
            hv[j] = h1u[(size_t)__shfl(s_reg, j) * 64 + ln];
#pragma unroll
        for (int j = 0; j < 16; j++) {
            float pj = __shfl(p, srcbase + j);
            ssum += pj;
            acc0 = fmaf(pj, __uint_as_float(hv[j] << 16), acc0);
            acc1 = fmaf(pj, __uint_as_float(hv[j] & 0xffff0000u), acc1);
        }
    }

    // tail: partial chunk
    if (base < e) {
        int cnt = e - base;
        int s_reg = esrc[base + (el < cnt ? el : 0)];
        float v = lrelu(als1[s_reg * 4 + h] + ad);
        if (el >= cnt) v = -1e30f;
        float cm = v;
        cm = fmaxf(cm, __shfl_xor(cm, 1));
        cm = fmaxf(cm, __shfl_xor(cm, 2));
        cm = fmaxf(cm, __shfl_xor(cm, 4));
        cm = fmaxf(cm, __shfl_xor(cm, 8));
        float nm = fmaxf(m, cm);
        float sc = __expf(m - nm);
        acc0 *= sc; acc1 *= sc; ssum *= sc;
        m = nm;
        float p = __expf(v - m);
        for (int j = 0; j < cnt; j++) {
            int   s  = __shfl(s_reg, j);
            float pj = __shfl(p, srcbase + j);
            uint hv = h1u[(size_t)s * 64 + ln];
            ssum += pj;
            acc0 = fmaf(pj, __uint_as_float(hv << 16), acc0);
            acc1 = fmaf(pj, __uint_as_float(hv & 0xffff0000u), acc1);
        }
    }

    float inv = 1.f / ssum;
    int c0 = ln * 2;
    float2 bb = *(const float2*)&b1[c0];
    float v0 = acc0 * inv + bb.x;
    float v1 = acc1 * inv + bb.y;
    v0 = (v0 > 0.f) ? v0 : (__expf(v0) - 1.f);   // ELU
    v1 = (v1 > 0.f) ? v1 : (__expf(v1) - 1.f);
    h1outu[(size_t)n * 64 + ln] = (uint)f2b(v0) | ((uint)f2b(v1) << 16);
}

// ---------------- layer 2 GEMM (+ fused logits) ----------------
__global__ __launch_bounds__(256) void k_gemm2(
        const ushort* __restrict__ h1outb, const float* __restrict__ W2,
        const float* __restrict__ a_src2, const float* __restrict__ a_dst2,
        ushort* __restrict__ h2b, float* __restrict__ als2, float* __restrict__ ald2) {
    __shared__ float hs[64][129];
    __shared__ float w2s[128][40];
    int t = threadIdx.x;
    int r0 = blockIdx.x * 64;
    for (int i = t; i < F1 * OUT_C; i += 256) w2s[i / 40][i % 40] = W2[i];
    for (int i = t; i < 64 * F1; i += 256) {
        int row = i >> 7, col = i & 127;
        int gr = r0 + row;
        hs[row][col] = (gr < N_NODES) ? b2f(h1outb[(size_t)gr * F1 + col]) : 0.f;
    }
    __syncthreads();
    int row = t >> 2;
    int cb  = (t & 3) * 10;
    float acc[10] = {};
    for (int k = 0; k < F1; k++) {
        float a = hs[row][k];
#pragma unroll
        for (int i = 0; i < 10; i++) acc[i] += a * w2s[k][cb + i];
    }
    int gr = r0 + row;
    float ps = 0.f, pd = 0.f;
#pragma unroll
    for (int i = 0; i < 10; i++) {
        ps += acc[i] * a_src2[cb + i];
        pd += acc[i] * a_dst2[cb + i];
    }
    ps += __shfl_xor(ps, 1); ps += __shfl_xor(ps, 2);
    pd += __shfl_xor(pd, 1); pd += __shfl_xor(pd, 2);
    if ((t & 3) == 0 && gr < N_NODES) { als2[gr] = ps; ald2[gr] = pd; }
    if (gr < N_NODES) {
#pragma unroll
        for (int i = 0; i < 10; i++) h2b[(size_t)gr * OUT_C + cb + i] = f2b(acc[i]);
    }
}

// ---------------- layer 2: fused online-softmax aggregation + log_softmax ----------------
// one wave per node; lane l<20: cols 2l,2l+1; chunks of 16 with batched loads.
__global__ __launch_bounds__(256) void k_agg2w(
        const int* __restrict__ rowptr, const int* __restrict__ esrc,
        const float* __restrict__ als2, const float* __restrict__ ald2,
        const uint* __restrict__ h2u, const float* __restrict__ b2,
        float* __restrict__ out) {
    int w = threadIdx.x >> 6, ln = threadIdx.x & 63;
    int n = blockIdx.x * 4 + w;
    if (n >= N_NODES) return;
    int b = rowptr[n], e = rowptr[n + 1];
    int el = ln & 15;
    float ad = ald2[n];
    bool act = ln < 20;

    float acc0 = 0.f, acc1 = 0.f, ssum = 0.f;
    float m = -1e30f;
    int base = b;

    for (; base + 16 <= e; base += 16) {
        int s_reg = esrc[base + el];
        float v = lrelu(als2[s_reg] + ad);
        float cm = v;
        cm = fmaxf(cm, __shfl_xor(cm, 1));
        cm = fmaxf(cm, __shfl_xor(cm, 2));
        cm = fmaxf(cm, __shfl_xor(cm, 4));
        cm = fmaxf(cm, __shfl_xor(cm, 8));
        float nm = fmaxf(m, cm);
        float sc = __expf(m - nm);
        acc0 *= sc; acc1 *= sc; ssum *= sc;
        m = nm;
        float p = __expf(v - m);
        uint hv[16];
#pragma unroll
        for (int j = 0; j < 16; j++)
            hv[j] = act ? h2u[(size_t)__shfl(s_reg, j) * 20 + ln] : 0u;
#pragma unroll
        for (int j = 0; j < 16; j++) {
            float pj = __shfl(p, j);
            ssum += pj;
            acc0 = fmaf(pj, __uint_as_float(hv[j] << 16), acc0);
            acc1 = fmaf(pj, __uint_as_float(hv[j] & 0xffff0000u), acc1);
        }
    }

    if (base < e) {
        int cnt = e - base;
        int s_reg = esrc[base + (el < cnt ? el : 0)];
        float v = lrelu(als2[s_reg] + ad);
        if (el >= cnt) v = -1e30f;
        float cm = v;
        cm = fmaxf(cm, __shfl_xor(cm, 1));
        cm = fmaxf(cm, __shfl_xor(cm, 2));
        cm = fmaxf(cm, __shfl_xor(cm, 4));
        cm = fmaxf(cm, __shfl_xor(cm, 8));
        float nm = fmaxf(m, cm);
        float sc = __expf(m - nm);
        acc0 *= sc; acc1 *= sc; ssum *= sc;
        m = nm;
        float p = __expf(v - m);
        for (int j = 0; j < cnt; j++) {
            int   s  = __shfl(s_reg, j);
            float pj = __shfl(p, j);
            uint hv = act ? h2u[(size_t)s * 20 + ln] : 0u;
            ssum += pj;
            acc0 = fmaf(pj, __uint_as_float(hv << 16), acc0);
            acc1 = fmaf(pj, __uint_as_float(hv & 0xffff0000u), acc1);
        }
    }

    float inv = 1.f / ssum;
    int c0 = ln * 2;
    float y0 = -1e30f, y1 = -1e30f;
    if (act) {
        y0 = acc0 * inv + b2[c0];
        y1 = acc1 * inv + b2[c0 + 1];
    }
    float mx = fmaxf(y0, y1);
#pragma unroll
    for (int off = 1; off < 64; off <<= 1) mx = fmaxf(mx, __shfl_xor(mx, off));
    float z = act ? (__expf(y0 - mx) + __expf(y1 - mx)) : 0.f;
#pragma unroll
    for (int off = 1; off < 64; off <<= 1) z += __shfl_xor(z, off);
    float lg = logf(z);
    if (act) {
        float2 o = make_float2(y0 - mx - lg, y1 - mx - lg);
        *(float2*)&out[(size_t)n * OUT_C + c0] = o;
    }
}

extern "C" void kernel_launch(void* const* d_in, const int* in_sizes, int n_in,
                              void* d_out, int out_size, void* d_ws, size_t ws_size,
                              hipStream_t stream) {
    const float* x      = (const float*)d_in[0];
    const int*   eidx   = (const int*)d_in[1];
    const float* W1     = (const float*)d_in[2];
    const float* a_src1 = (const float*)d_in[3];
    const float* a_dst1 = (const float*)d_in[4];
    const float* b1     = (const float*)d_in[5];
    const float* W2     = (const float*)d_in[6];
    const float* a_src2 = (const float*)d_in[7];
    const float* a_dst2 = (const float*)d_in[8];
    const float* b2     = (const float*)d_in[9];
    float* out = (float*)d_out;

    // workspace layout
    float* wf    = (float*)d_ws;
    float* als1  = wf;                   // 200,000
    float* ald1  = wf + 200000;          // 200,000
    float* als2  = wf + 400000;          // 50,000
    float* ald2  = wf + 450000;          // 50,000
    ushort* h1b    = (ushort*)(wf + 500000);   // 6,400,000 ushorts
    ushort* h1outb = h1b + 6400000;            // 6,400,000
    ushort* h2b    = h1outb + 6400000;         // 2,000,000
    ushort* W1T    = h2b + 2000000;            // 32,768
    int* ip      = (int*)(W1T + 32768);
    int* rowptr  = ip;                   // 50,001
    int* cnt     = ip + 50001;           // 50,000
    int* cursor  = ip + 100001;          // 50,000
    int* esrc    = ip + 150001;          // 850,000
    int* bsums   = ip + 1000001;         // 256

    // graph build
    k_init   <<<196, 256, 0, stream>>>(cnt, cursor);
    k_deg    <<<(N_EDGE + 255) / 256, 256, 0, stream>>>(eidx, cnt);
    k_scan1  <<<196, 256, 0, stream>>>(cnt, rowptr, bsums);
    k_scan2  <<<1, 256, 0, stream>>>(bsums);
    k_scan3  <<<196, 256, 0, stream>>>(rowptr, bsums);
    k_scatter<<<(ET + 255) / 256, 256, 0, stream>>>(eidx, rowptr, cursor, esrc);

    // layer 1
    k_prepW1<<<(F1 * IN_DIM + 255) / 256, 256, 0, stream>>>(W1, W1T);
    k_gemm1m<<<(N_NODES + 63) / 64, 256, 0, stream>>>(x, W1T, a_src1, a_dst1, h1b, als1, ald1);
    k_agg1w<<<(N_NODES + 3) / 4, 256, 0, stream>>>(rowptr, esrc, als1, ald1,
                                                   (const uint*)h1b, b1, (uint*)h1outb);

    // layer 2
    k_gemm2<<<(N_NODES + 63) / 64, 256, 0, stream>>>(h1outb, W2, a_src2, a_dst2, h2b, als2, ald2);
    k_agg2w<<<(N_NODES + 3) / 4, 256, 0, stream>>>(rowptr, esrc, als2, ald2,
                                                   (const uint*)h2b, b2, out);
}

// Round 6
// 340.229 us; speedup vs baseline: 1.3687x; 1.0221x over previous
//
#include <hip/hip_runtime.h>
#include <hip/hip_bf16.h>

#define N_NODES 50000
#define N_EDGE  800000
#define ET      850000          // N_EDGE + N_NODES self loops
#define IN_DIM  256
#define F1      128             // H1*C1
#define NHEAD   4
#define C1      32
#define OUT_C   40
#define NEG     0.2f
#define P8      50048           // padded slice stride (line-aligned: 50048*4 % 64 == 0)
#define NSEG    400000          // N_NODES * 8 sub-segments

typedef __bf16 bf16_8 __attribute__((ext_vector_type(8)));
typedef float  f32x4  __attribute__((ext_vector_type(4)));

static __device__ __forceinline__ ushort f2b(float f) {
    __hip_bfloat16 h = __float2bfloat16(f);
    return *reinterpret_cast<ushort*>(&h);
}
static __device__ __forceinline__ float b2f(ushort u) {
    unsigned v = ((unsigned)u) << 16;
    return __uint_as_float(v);
}
static __device__ __forceinline__ float lrelu(float v) {
    return (v > 0.f) ? v : NEG * v;
}

// ---------------- graph build (XCD-local sub-segmented CSR) ----------------
// Each node's segment is split into 8 sub-segments keyed by x=(e>>8)&7 (edge-block
// index mod 8 ~ XCD id under round-robin dispatch). Atomic counters live in
// per-x slices c8[x*P8+d] so counter lines are touched by (heuristically) one
// XCD only; esrc sub-segments likewise get single-XCD writes. Correctness does
// not depend on the dispatch mapping — x is derived from the edge index alone.

__global__ void k_initX(int* c) {                 // zero c8 + cur8 (contiguous)
    int i = blockIdx.x * 1024 + threadIdx.x;
    if (i < 2 * 8 * P8) c[i] = 0;
}

__global__ void k_degX(const int* __restrict__ eidx, int* __restrict__ c8) {
    int e = blockIdx.x * 256 + threadIdx.x;
    if (e >= ET) return;
    int d = (e < N_EDGE) ? eidx[N_EDGE + e] : e - N_EDGE;
    int x = (e >> 8) & 7;
    atomicAdd(&c8[x * P8 + d], 1);
}

// exclusive scan over NSEG values in (d,x)-major order: val(i)=c8[(i&7)*P8+(i>>3)]
__global__ __launch_bounds__(1024) void k_scanA(const int* __restrict__ c8,
                                                int* __restrict__ rp8, int* __restrict__ bs) {
    __shared__ int sh[1024];
    int t = threadIdx.x;
    int i = blockIdx.x * 1024 + t;
    int v = (i < NSEG) ? c8[(i & 7) * P8 + (i >> 3)] : 0;
    sh[t] = v; __syncthreads();
    for (int off = 1; off < 1024; off <<= 1) {
        int x = (t >= off) ? sh[t - off] : 0;
        __syncthreads();
        sh[t] += x;
        __syncthreads();
    }
    if (i < NSEG) rp8[i] = sh[t] - v;            // exclusive
    if (t == 1023) bs[blockIdx.x] = sh[t];
}

__global__ __launch_bounds__(1024) void k_scanB(int* bs) {   // 391 partials
    __shared__ int sh[1024];
    int t = threadIdx.x;
    int v = (t < 391) ? bs[t] : 0;
    sh[t] = v; __syncthreads();
    for (int off = 1; off < 1024; off <<= 1) {
        int x = (t >= off) ? sh[t - off] : 0;
        __syncthreads();
        sh[t] += x;
        __syncthreads();
    }
    if (t < 391) bs[t] = sh[t] - v;              // exclusive
}

__global__ __launch_bounds__(1024) void k_scanC(int* __restrict__ rp8,
                                                const int* __restrict__ bs) {
    int i = blockIdx.x * 1024 + threadIdx.x;
    if (i < NSEG) rp8[i] += bs[blockIdx.x];
    if (i == 0) rp8[NSEG] = ET;
}

__global__ void k_scatterX(const int* __restrict__ eidx, const int* __restrict__ rp8,
                           int* __restrict__ cur8, int* __restrict__ esrc) {
    int e = blockIdx.x * 256 + threadIdx.x;
    if (e >= ET) return;
    int s, d;
    if (e < N_EDGE) { s = eidx[e]; d = eidx[N_EDGE + e]; }
    else            { s = e - N_EDGE; d = s; }
    int x = (e >> 8) & 7;
    int pos = rp8[d * 8 + x] + atomicAdd(&cur8[x * P8 + d], 1);
    esrc[pos] = s;
}

// ---------------- prep: W1 -> bf16 transposed [n][k] ----------------
__global__ void k_prepW1(const float* __restrict__ W1, ushort* __restrict__ W1T) {
    int i = blockIdx.x * 256 + threadIdx.x;      // i = n*256 + k
    if (i >= F1 * IN_DIM) return;
    int n = i >> 8, k = i & 255;
    W1T[i] = f2b(W1[k * F1 + n]);
}

// ---------------- layer 1 GEMM via MFMA (+ fused attention logits) ----------------
__global__ __launch_bounds__(256) void k_gemm1m(
        const float* __restrict__ x, const ushort* __restrict__ W1T,
        const float* __restrict__ a_src1, const float* __restrict__ a_dst1,
        ushort* __restrict__ h1b, float* __restrict__ als1, float* __restrict__ ald1) {
    __shared__ ushort As[64 * 40];   // [row][k], pad 32->40 to break bank stride
    __shared__ ushort Bs[128 * 40];  // [n][k]
    int t = threadIdx.x;
    int w = t >> 6, lane = t & 63;
    int cl = lane & 15, q = lane >> 4;
    int r0 = blockIdx.x * 64;

    f32x4 acc[8];
#pragma unroll
    for (int i = 0; i < 8; i++) acc[i] = (f32x4){0.f, 0.f, 0.f, 0.f};

    int arow = t >> 2;               // A staging: row, 8 consecutive k
    int akp  = (t & 3) * 8;
    int brow = t >> 1;               // B staging: n, 16 consecutive k
    int bkp  = (t & 1) * 16;
    int agr  = r0 + arow;

    for (int kc = 0; kc < IN_DIM; kc += 32) {
        float4 f0, f1;
        if (agr < N_NODES) {
            f0 = *(const float4*)&x[(size_t)agr * IN_DIM + kc + akp];
            f1 = *(const float4*)&x[(size_t)agr * IN_DIM + kc + akp + 4];
        } else {
            f0 = make_float4(0.f, 0.f, 0.f, 0.f);
            f1 = f0;
        }
        ushort4 u0 = {f2b(f0.x), f2b(f0.y), f2b(f0.z), f2b(f0.w)};
        ushort4 u1 = {f2b(f1.x), f2b(f1.y), f2b(f1.z), f2b(f1.w)};
        *(ushort4*)&As[arow * 40 + akp]     = u0;
        *(ushort4*)&As[arow * 40 + akp + 4] = u1;

        *(uint4*)&Bs[brow * 40 + bkp]     = *(const uint4*)&W1T[brow * IN_DIM + kc + bkp];
        *(uint4*)&Bs[brow * 40 + bkp + 8] = *(const uint4*)&W1T[brow * IN_DIM + kc + bkp + 8];
        __syncthreads();

        bf16_8 af = *(bf16_8*)&As[(w * 16 + cl) * 40 + q * 8];
#pragma unroll
        for (int ct = 0; ct < 8; ct++) {
            bf16_8 bfr = *(bf16_8*)&Bs[(ct * 16 + cl) * 40 + q * 8];
            acc[ct] = __builtin_amdgcn_mfma_f32_16x16x32_bf16(af, bfr, acc[ct], 0, 0, 0);
        }
        __syncthreads();
    }

    float asv[8], adv[8];
#pragma unroll
    for (int ct = 0; ct < 8; ct++) {
        asv[ct] = a_src1[ct * 16 + cl];
        adv[ct] = a_dst1[ct * 16 + cl];
    }

#pragma unroll
    for (int reg = 0; reg < 4; reg++) {
        int grow = r0 + w * 16 + q * 4 + reg;
        bool ok = grow < N_NODES;
        float ps[4] = {0.f, 0.f, 0.f, 0.f};
        float pd[4] = {0.f, 0.f, 0.f, 0.f};
#pragma unroll
        for (int ct = 0; ct < 8; ct++) {
            float v = acc[ct][reg];
            if (ok) h1b[(size_t)grow * F1 + ct * 16 + cl] = f2b(v);
            ps[ct >> 1] += v * asv[ct];
            pd[ct >> 1] += v * adv[ct];
        }
#pragma unroll
        for (int hh = 0; hh < 4; hh++) {
            ps[hh] += __shfl_xor(ps[hh], 1); ps[hh] += __shfl_xor(ps[hh], 2);
            ps[hh] += __shfl_xor(ps[hh], 4); ps[hh] += __shfl_xor(ps[hh], 8);
            pd[hh] += __shfl_xor(pd[hh], 1); pd[hh] += __shfl_xor(pd[hh], 2);
            pd[hh] += __shfl_xor(pd[hh], 4); pd[hh] += __shfl_xor(pd[hh], 8);
        }
        if (cl == 0 && ok) {
#pragma unroll
            for (int hh = 0; hh < 4; hh++) {
                als1[grow * NHEAD + hh] = ps[hh];
                ald1[grow * NHEAD + hh] = pd[hh];
            }
        }
    }
}

// ---------------- layer 1: fused online-softmax aggregation, one wave per node ----------------
__global__ __launch_bounds__(256) void k_agg1w(
        const int* __restrict__ rp8, const int* __restrict__ esrc,
        const float* __restrict__ als1, const float* __restrict__ ald1,
        const uint* __restrict__ h1u, const float* __restrict__ b1,
        uint* __restrict__ h1outu) {
    int w = threadIdx.x >> 6, ln = threadIdx.x & 63;
    int n = blockIdx.x * 4 + w;
    if (n >= N_NODES) return;
    int b = rp8[n << 3], e = rp8[(n << 3) + 8];
    int h  = ln >> 4;           // head for this lane
    int el = ln & 15;           // edge slot within chunk
    int srcbase = ln & 48;      // lane holding (h, edge j) is srcbase + j
    float ad = ald1[n * 4 + h];

    float acc0 = 0.f, acc1 = 0.f, ssum = 0.f;
    float m = -1e30f;
    int base = b;

    // fast path: full chunks of 16, loads batched
    for (; base + 16 <= e; base += 16) {
        int s_reg = esrc[base + el];
        float v = lrelu(als1[s_reg * 4 + h] + ad);
        float cm = v;
        cm = fmaxf(cm, __shfl_xor(cm, 1));
        cm = fmaxf(cm, __shfl_xor(cm, 2));
        cm = fmaxf(cm, __shfl_xor(cm, 4));
        cm = fmaxf(cm, __shfl_xor(cm, 8));
        float nm = fmaxf(m, cm);
        float sc = __expf(m - nm);
        acc0 *= sc; acc1 *= sc; ssum *= sc;
        m = nm;
        float p = __expf(v - m);
        uint hv[16];
#pragma unroll
        for (int j = 0; j < 16; j++)
            hv[j] = h1u[(size_t)__shfl(s_reg, j) * 64 + ln];
#pragma unroll
        for (int j = 0; j < 16; j++) {
            float pj = __shfl(p, srcbase + j);
            ssum += pj;
            acc0 = fmaf(pj, __uint_as_float(hv[j] << 16), acc0);
            acc1 = fmaf(pj, __uint_as_float(hv[j] & 0xffff0000u), acc1);
        }
    }

    // tail: partial chunk
    if (base < e) {
        int cnt = e - base;
        int s_reg = esrc[base + (el < cnt ? el : 0)];
        float v = lrelu(als1[s_reg * 4 + h] + ad);
        if (el >= cnt) v = -1e30f;
        float cm = v;
        cm = fmaxf(cm, __shfl_xor(cm, 1));
        cm = fmaxf(cm, __shfl_xor(cm, 2));
        cm = fmaxf(cm, __shfl_xor(cm, 4));
        cm = fmaxf(cm, __shfl_xor(cm, 8));
        float nm = fmaxf(m, cm);
        float sc = __expf(m - nm);
        acc0 *= sc; acc1 *= sc; ssum *= sc;
        m = nm;
        float p = __expf(v - m);
        for (int j = 0; j < cnt; j++) {
            int   s  = __shfl(s_reg, j);
            float pj = __shfl(p, srcbase + j);
            uint hv = h1u[(size_t)s * 64 + ln];
            ssum += pj;
            acc0 = fmaf(pj, __uint_as_float(hv << 16), acc0);
            acc1 = fmaf(pj, __uint_as_float(hv & 0xffff0000u), acc1);
        }
    }

    float inv = 1.f / ssum;
    int c0 = ln * 2;
    float2 bb = *(const float2*)&b1[c0];
    float v0 = acc0 * inv + bb.x;
    float v1 = acc1 * inv + bb.y;
    v0 = (v0 > 0.f) ? v0 : (__expf(v0) - 1.f);   // ELU
    v1 = (v1 > 0.f) ? v1 : (__expf(v1) - 1.f);
    h1outu[(size_t)n * 64 + ln] = (uint)f2b(v0) | ((uint)f2b(v1) << 16);
}

// ---------------- layer 2 GEMM (+ fused logits) ----------------
__global__ __launch_bounds__(256) void k_gemm2(
        const ushort* __restrict__ h1outb, const float* __restrict__ W2,
        const float* __restrict__ a_src2, const float* __restrict__ a_dst2,
        ushort* __restrict__ h2b, float* __restrict__ als2, float* __restrict__ ald2) {
    __shared__ float hs[64][129];
    __shared__ float w2s[128][40];
    int t = threadIdx.x;
    int r0 = blockIdx.x * 64;
    for (int i = t; i < F1 * OUT_C; i += 256) w2s[i / 40][i % 40] = W2[i];
    for (int i = t; i < 64 * F1; i += 256) {
        int row = i >> 7, col = i & 127;
        int gr = r0 + row;
        hs[row][col] = (gr < N_NODES) ? b2f(h1outb[(size_t)gr * F1 + col]) : 0.f;
    }
    __syncthreads();
    int row = t >> 2;
    int cb  = (t & 3) * 10;
    float acc[10] = {};
    for (int k = 0; k < F1; k++) {
        float a = hs[row][k];
#pragma unroll
        for (int i = 0; i < 10; i++) acc[i] += a * w2s[k][cb + i];
    }
    int gr = r0 + row;
    float ps = 0.f, pd = 0.f;
#pragma unroll
    for (int i = 0; i < 10; i++) {
        ps += acc[i] * a_src2[cb + i];
        pd += acc[i] * a_dst2[cb + i];
    }
    ps += __shfl_xor(ps, 1); ps += __shfl_xor(ps, 2);
    pd += __shfl_xor(pd, 1); pd += __shfl_xor(pd, 2);
    if ((t & 3) == 0 && gr < N_NODES) { als2[gr] = ps; ald2[gr] = pd; }
    if (gr < N_NODES) {
#pragma unroll
        for (int i = 0; i < 10; i++) h2b[(size_t)gr * OUT_C + cb + i] = f2b(acc[i]);
    }
}

// ---------------- layer 2: fused online-softmax aggregation + log_softmax ----------------
__global__ __launch_bounds__(256) void k_agg2w(
        const int* __restrict__ rp8, const int* __restrict__ esrc,
        const float* __restrict__ als2, const float* __restrict__ ald2,
        const uint* __restrict__ h2u, const float* __restrict__ b2,
        float* __restrict__ out) {
    int w = threadIdx.x >> 6, ln = threadIdx.x & 63;
    int n = blockIdx.x * 4 + w;
    if (n >= N_NODES) return;
    int b = rp8[n << 3], e = rp8[(n << 3) + 8];
    int el = ln & 15;
    float ad = ald2[n];
    bool act = ln < 20;

    float acc0 = 0.f, acc1 = 0.f, ssum = 0.f;
    float m = -1e30f;
    int base = b;

    for (; base + 16 <= e; base += 16) {
        int s_reg = esrc[base + el];
        float v = lrelu(als2[s_reg] + ad);
        float cm = v;
        cm = fmaxf(cm, __shfl_xor(cm, 1));
        cm = fmaxf(cm, __shfl_xor(cm, 2));
        cm = fmaxf(cm, __shfl_xor(cm, 4));
        cm = fmaxf(cm, __shfl_xor(cm, 8));
        float nm = fmaxf(m, cm);
        float sc = __expf(m - nm);
        acc0 *= sc; acc1 *= sc; ssum *= sc;
        m = nm;
        float p = __expf(v - m);
        uint hv[16];
#pragma unroll
        for (int j = 0; j < 16; j++)
            hv[j] = act ? h2u[(size_t)__shfl(s_reg, j) * 20 + ln] : 0u;
#pragma unroll
        for (int j = 0; j < 16; j++) {
            float pj = __shfl(p, j);
            ssum += pj;
            acc0 = fmaf(pj, __uint_as_float(hv[j] << 16), acc0);
            acc1 = fmaf(pj, __uint_as_float(hv[j] & 0xffff0000u), acc1);
        }
    }

    if (base < e) {
        int cnt = e - base;
        int s_reg = esrc[base + (el < cnt ? el : 0)];
        float v = lrelu(als2[s_reg] + ad);
        if (el >= cnt) v = -1e30f;
        float cm = v;
        cm = fmaxf(cm, __shfl_xor(cm, 1));
        cm = fmaxf(cm, __shfl_xor(cm, 2));
        cm = fmaxf(cm, __shfl_xor(cm, 4));
        cm = fmaxf(cm, __shfl_xor(cm, 8));
        float nm = fmaxf(m, cm);
        float sc = __expf(m - nm);
        acc0 *= sc; acc1 *= sc; ssum *= sc;
        m = nm;
        float p = __expf(v - m);
        for (int j = 0; j < cnt; j++) {
            int   s  = __shfl(s_reg, j);
            float pj = __shfl(p, j);
            uint hv = act ? h2u[(size_t)s * 20 + ln] : 0u;
            ssum += pj;
            acc0 = fmaf(pj, __uint_as_float(hv << 16), acc0);
            acc1 = fmaf(pj, __uint_as_float(hv & 0xffff0000u), acc1);
        }
    }

    float inv = 1.f / ssum;
    int c0 = ln * 2;
    float y0 = -1e30f, y1 = -1e30f;
    if (act) {
        y0 = acc0 * inv + b2[c0];
        y1 = acc1 * inv + b2[c0 + 1];
    }
    float mx = fmaxf(y0, y1);
#pragma unroll
    for (int off = 1; off < 64; off <<= 1) mx = fmaxf(mx, __shfl_xor(mx, off));
    float z = act ? (__expf(y0 - mx) + __expf(y1 - mx)) : 0.f;
#pragma unroll
    for (int off = 1; off < 64; off <<= 1) z += __shfl_xor(z, off);
    float lg = logf(z);
    if (act) {
        float2 o = make_float2(y0 - mx - lg, y1 - mx - lg);
        *(float2*)&out[(size_t)n * OUT_C + c0] = o;
    }
}

extern "C" void kernel_launch(void* const* d_in, const int* in_sizes, int n_in,
                              void* d_out, int out_size, void* d_ws, size_t ws_size,
                              hipStream_t stream) {
    const float* x      = (const float*)d_in[0];
    const int*   eidx   = (const int*)d_in[1];
    const float* W1     = (const float*)d_in[2];
    const float* a_src1 = (const float*)d_in[3];
    const float* a_dst1 = (const float*)d_in[4];
    const float* b1     = (const float*)d_in[5];
    const float* W2     = (const float*)d_in[6];
    const float* a_src2 = (const float*)d_in[7];
    const float* a_dst2 = (const float*)d_in[8];
    const float* b2     = (const float*)d_in[9];
    float* out = (float*)d_out;

    // workspace layout
    float* wf    = (float*)d_ws;
    float* als1  = wf;                   // 200,000
    float* ald1  = wf + 200000;          // 200,000
    float* als2  = wf + 400000;          // 50,000
    float* ald2  = wf + 450000;          // 50,000
    ushort* h1b    = (ushort*)(wf + 500000);   // 6,400,000 ushorts
    ushort* h1outb = h1b + 6400000;            // 6,400,000
    ushort* h2b    = h1outb + 6400000;         // 2,000,000
    ushort* W1T    = h2b + 2000000;            // 32,768
    int* ip      = (int*)(W1T + 32768);
    int* rp8     = ip;                   // 400,001
    int* c8      = ip + 400064;          // 400,384 (8 * P8)
    int* cur8    = ip + 800448;          // 400,384 (contiguous after c8)
    int* esrc    = ip + 1200832;         // 850,000
    int* bs      = ip + 2050832;         // 1,024

    // graph build (XCD-local sub-segmented CSR)
    k_initX   <<<(2 * 8 * P8 + 1023) / 1024, 1024, 0, stream>>>(c8);
    k_degX    <<<(ET + 255) / 256, 256, 0, stream>>>(eidx, c8);
    k_scanA   <<<(NSEG + 1023) / 1024, 1024, 0, stream>>>(c8, rp8, bs);
    k_scanB   <<<1, 1024, 0, stream>>>(bs);
    k_scanC   <<<(NSEG + 1023) / 1024, 1024, 0, stream>>>(rp8, bs);
    k_scatterX<<<(ET + 255) / 256, 256, 0, stream>>>(eidx, rp8, cur8, esrc);

    // layer 1
    k_prepW1<<<(F1 * IN_DIM + 255) / 256, 256, 0, stream>>>(W1, W1T);
    k_gemm1m<<<(N_NODES + 63) / 64, 256, 0, stream>>>(x, W1T, a_src1, a_dst1, h1b, als1, ald1);
    k_agg1w<<<(N_NODES + 3) / 4, 256, 0, stream>>>(rp8, esrc, als1, ald1,
                                                   (const uint*)h1b, b1, (uint*)h1outb);

    // layer 2
    k_gemm2<<<(N_NODES + 63) / 64, 256, 0, stream>>>(h1outb, W2, a_src2, a_dst2, h2b, als2, ald2);
    k_agg2w<<<(N_NODES + 3) / 4, 256, 0, stream>>>(rp8, esrc, als2, ald2,
                                                   (const uint*)h2b, b2, out);
}

// Round 7
// 325.064 us; speedup vs baseline: 1.4326x; 1.0467x over previous
//
#include <hip/hip_runtime.h>
#include <hip/hip_bf16.h>

#define N_NODES 50000
#define N_EDGE  800000
#define ET      850000          // N_EDGE + N_NODES self loops
#define IN_DIM  256
#define F1      128             // H1*C1
#define NHEAD   4
#define C1      32
#define OUT_C   40
#define NEG     0.2f
#define P8      50048           // padded slice stride (line-aligned: 50048*4 % 64 == 0)
#define NSEG    400000          // N_NODES * 8 sub-segments

typedef __bf16 bf16_8 __attribute__((ext_vector_type(8)));
typedef float  f32x4  __attribute__((ext_vector_type(4)));

static __device__ __forceinline__ ushort f2b(float f) {
    __hip_bfloat16 h = __float2bfloat16(f);
    return *reinterpret_cast<ushort*>(&h);
}
static __device__ __forceinline__ float b2f(ushort u) {
    unsigned v = ((unsigned)u) << 16;
    return __uint_as_float(v);
}
static __device__ __forceinline__ float lrelu(float v) {
    return (v > 0.f) ? v : NEG * v;
}

// ---------------- graph build (XCD-local sub-segmented CSR) ----------------
__global__ void k_initX(int* c) {                 // zero c8 + cur8 (contiguous)
    int i = blockIdx.x * 1024 + threadIdx.x;
    if (i < 2 * 8 * P8) c[i] = 0;
}

__global__ void k_degX(const int* __restrict__ eidx, int* __restrict__ c8) {
    int e = blockIdx.x * 256 + threadIdx.x;
    if (e >= ET) return;
    int d = (e < N_EDGE) ? eidx[N_EDGE + e] : e - N_EDGE;
    int x = (e >> 8) & 7;
    atomicAdd(&c8[x * P8 + d], 1);
}

// exclusive scan over NSEG values in (d,x)-major order: val(i)=c8[(i&7)*P8+(i>>3)]
__global__ __launch_bounds__(1024) void k_scanA(const int* __restrict__ c8,
                                                int* __restrict__ rp8, int* __restrict__ bs) {
    __shared__ int sh[1024];
    int t = threadIdx.x;
    int i = blockIdx.x * 1024 + t;
    int v = (i < NSEG) ? c8[(i & 7) * P8 + (i >> 3)] : 0;
    sh[t] = v; __syncthreads();
    for (int off = 1; off < 1024; off <<= 1) {
        int x = (t >= off) ? sh[t - off] : 0;
        __syncthreads();
        sh[t] += x;
        __syncthreads();
    }
    if (i < NSEG) rp8[i] = sh[t] - v;            // exclusive
    if (t == 1023) bs[blockIdx.x] = sh[t];
}

__global__ __launch_bounds__(1024) void k_scanB(int* bs) {   // 391 partials
    __shared__ int sh[1024];
    int t = threadIdx.x;
    int v = (t < 391) ? bs[t] : 0;
    sh[t] = v; __syncthreads();
    for (int off = 1; off < 1024; off <<= 1) {
        int x = (t >= off) ? sh[t - off] : 0;
        __syncthreads();
        sh[t] += x;
        __syncthreads();
    }
    if (t < 391) bs[t] = sh[t] - v;              // exclusive
}

__global__ __launch_bounds__(1024) void k_scanC(int* __restrict__ rp8,
                                                const int* __restrict__ bs) {
    int i = blockIdx.x * 1024 + threadIdx.x;
    if (i < NSEG) rp8[i] += bs[blockIdx.x];
    if (i == 0) rp8[NSEG] = ET;
}

__global__ void k_scatterX(const int* __restrict__ eidx, const int* __restrict__ rp8,
                           int* __restrict__ cur8, int* __restrict__ esrc) {
    int e = blockIdx.x * 256 + threadIdx.x;
    if (e >= ET) return;
    int s, d;
    if (e < N_EDGE) { s = eidx[e]; d = eidx[N_EDGE + e]; }
    else            { s = e - N_EDGE; d = s; }
    int x = (e >> 8) & 7;
    int pos = rp8[d * 8 + x] + atomicAdd(&cur8[x * P8 + d], 1);
    esrc[pos] = s;
}

// ---------------- prep: W1 -> bf16 transposed [n][k] ----------------
__global__ void k_prepW1(const float* __restrict__ W1, ushort* __restrict__ W1T) {
    int i = blockIdx.x * 256 + threadIdx.x;      // i = n*256 + k
    if (i >= F1 * IN_DIM) return;
    int n = i >> 8, k = i & 255;
    W1T[i] = f2b(W1[k * F1 + n]);
}

// ---------------- layer 1 GEMM via MFMA (+ fused attention logits) ----------------
__global__ __launch_bounds__(256) void k_gemm1m(
        const float* __restrict__ x, const ushort* __restrict__ W1T,
        const float* __restrict__ a_src1, const float* __restrict__ a_dst1,
        ushort* __restrict__ h1b, float* __restrict__ als1, float* __restrict__ ald1) {
    __shared__ ushort As[64 * 40];   // [row][k], pad 32->40 to break bank stride
    __shared__ ushort Bs[128 * 40];  // [n][k]
    int t = threadIdx.x;
    int w = t >> 6, lane = t & 63;
    int cl = lane & 15, q = lane >> 4;
    int r0 = blockIdx.x * 64;

    f32x4 acc[8];
#pragma unroll
    for (int i = 0; i < 8; i++) acc[i] = (f32x4){0.f, 0.f, 0.f, 0.f};

    int arow = t >> 2;               // A staging: row, 8 consecutive k
    int akp  = (t & 3) * 8;
    int brow = t >> 1;               // B staging: n, 16 consecutive k
    int bkp  = (t & 1) * 16;
    int agr  = r0 + arow;

    for (int kc = 0; kc < IN_DIM; kc += 32) {
        float4 f0, f1;
        if (agr < N_NODES) {
            f0 = *(const float4*)&x[(size_t)agr * IN_DIM + kc + akp];
            f1 = *(const float4*)&x[(size_t)agr * IN_DIM + kc + akp + 4];
        } else {
            f0 = make_float4(0.f, 0.f, 0.f, 0.f);
            f1 = f0;
        }
        ushort4 u0 = {f2b(f0.x), f2b(f0.y), f2b(f0.z), f2b(f0.w)};
        ushort4 u1 = {f2b(f1.x), f2b(f1.y), f2b(f1.z), f2b(f1.w)};
        *(ushort4*)&As[arow * 40 + akp]     = u0;
        *(ushort4*)&As[arow * 40 + akp + 4] = u1;

        *(uint4*)&Bs[brow * 40 + bkp]     = *(const uint4*)&W1T[brow * IN_DIM + kc + bkp];
        *(uint4*)&Bs[brow * 40 + bkp + 8] = *(const uint4*)&W1T[brow * IN_DIM + kc + bkp + 8];
        __syncthreads();

        bf16_8 af = *(bf16_8*)&As[(w * 16 + cl) * 40 + q * 8];
#pragma unroll
        for (int ct = 0; ct < 8; ct++) {
            bf16_8 bfr = *(bf16_8*)&Bs[(ct * 16 + cl) * 40 + q * 8];
            acc[ct] = __builtin_amdgcn_mfma_f32_16x16x32_bf16(af, bfr, acc[ct], 0, 0, 0);
        }
        __syncthreads();
    }

    float asv[8], adv[8];
#pragma unroll
    for (int ct = 0; ct < 8; ct++) {
        asv[ct] = a_src1[ct * 16 + cl];
        adv[ct] = a_dst1[ct * 16 + cl];
    }

#pragma unroll
    for (int reg = 0; reg < 4; reg++) {
        int grow = r0 + w * 16 + q * 4 + reg;
        bool ok = grow < N_NODES;
        float ps[4] = {0.f, 0.f, 0.f, 0.f};
        float pd[4] = {0.f, 0.f, 0.f, 0.f};
#pragma unroll
        for (int ct = 0; ct < 8; ct++) {
            float v = acc[ct][reg];
            if (ok) h1b[(size_t)grow * F1 + ct * 16 + cl] = f2b(v);
            ps[ct >> 1] += v * asv[ct];
            pd[ct >> 1] += v * adv[ct];
        }
#pragma unroll
        for (int hh = 0; hh < 4; hh++) {
            ps[hh] += __shfl_xor(ps[hh], 1); ps[hh] += __shfl_xor(ps[hh], 2);
            ps[hh] += __shfl_xor(ps[hh], 4); ps[hh] += __shfl_xor(ps[hh], 8);
            pd[hh] += __shfl_xor(pd[hh], 1); pd[hh] += __shfl_xor(pd[hh], 2);
            pd[hh] += __shfl_xor(pd[hh], 4); pd[hh] += __shfl_xor(pd[hh], 8);
        }
        if (cl == 0 && ok) {
#pragma unroll
            for (int hh = 0; hh < 4; hh++) {
                als1[grow * NHEAD + hh] = ps[hh];
                ald1[grow * NHEAD + hh] = pd[hh];
            }
        }
    }
}

// ---------------- layer 1: fused online-softmax aggregation, one wave per node ----------------
// Both full chunks AND the tail use the batched 16-slot gather (tail loads
// guarded by j<cnt; inactive slots have p=0 via v=-1e30), so no serial
// load->waitcnt->fma chain anywhere.
__global__ __launch_bounds__(256) void k_agg1w(
        const int* __restrict__ rp8, const int* __restrict__ esrc,
        const float* __restrict__ als1, const float* __restrict__ ald1,
        const uint* __restrict__ h1u, const float* __restrict__ b1,
        uint* __restrict__ h1outu) {
    int w = threadIdx.x >> 6, ln = threadIdx.x & 63;
    int n = blockIdx.x * 4 + w;
    if (n >= N_NODES) return;
    int b = rp8[n << 3], e = rp8[(n << 3) + 8];
    int h  = ln >> 4;           // head for this lane
    int el = ln & 15;           // edge slot within chunk
    int srcbase = ln & 48;      // lane holding (h, edge j) is srcbase + j
    float ad = ald1[n * 4 + h];

    float acc0 = 0.f, acc1 = 0.f, ssum = 0.f;
    float m = -1e30f;
    int base = b;

    // fast path: full chunks of 16, loads batched
    for (; base + 16 <= e; base += 16) {
        int s_reg = esrc[base + el];
        float v = lrelu(als1[s_reg * 4 + h] + ad);
        float cm = v;
        cm = fmaxf(cm, __shfl_xor(cm, 1));
        cm = fmaxf(cm, __shfl_xor(cm, 2));
        cm = fmaxf(cm, __shfl_xor(cm, 4));
        cm = fmaxf(cm, __shfl_xor(cm, 8));
        float nm = fmaxf(m, cm);
        float sc = __expf(m - nm);
        acc0 *= sc; acc1 *= sc; ssum *= sc;
        m = nm;
        float p = __expf(v - m);
        uint hv[16];
#pragma unroll
        for (int j = 0; j < 16; j++)
            hv[j] = h1u[(size_t)__shfl(s_reg, j) * 64 + ln];
#pragma unroll
        for (int j = 0; j < 16; j++) {
            float pj = __shfl(p, srcbase + j);
            ssum += pj;
            acc0 = fmaf(pj, __uint_as_float(hv[j] << 16), acc0);
            acc1 = fmaf(pj, __uint_as_float(hv[j] & 0xffff0000u), acc1);
        }
    }

    // tail: partial chunk, batched like the fast path
    if (base < e) {
        int cnt = e - base;
        int s_reg = esrc[base + (el < cnt ? el : 0)];
        float v = lrelu(als1[s_reg * 4 + h] + ad);
        if (el >= cnt) v = -1e30f;
        float cm = v;
        cm = fmaxf(cm, __shfl_xor(cm, 1));
        cm = fmaxf(cm, __shfl_xor(cm, 2));
        cm = fmaxf(cm, __shfl_xor(cm, 4));
        cm = fmaxf(cm, __shfl_xor(cm, 8));
        float nm = fmaxf(m, cm);
        float sc = __expf(m - nm);
        acc0 *= sc; acc1 *= sc; ssum *= sc;
        m = nm;
        float p = __expf(v - m);            // 0 for inactive slots
        uint hv[16];
#pragma unroll
        for (int j = 0; j < 16; j++)
            hv[j] = (j < cnt) ? h1u[(size_t)__shfl(s_reg, j) * 64 + ln] : 0u;
#pragma unroll
        for (int j = 0; j < 16; j++) {
            float pj = __shfl(p, srcbase + j);   // 0 for j>=cnt
            ssum += pj;
            acc0 = fmaf(pj, __uint_as_float(hv[j] << 16), acc0);
            acc1 = fmaf(pj, __uint_as_float(hv[j] & 0xffff0000u), acc1);
        }
    }

    float inv = 1.f / ssum;
    int c0 = ln * 2;
    float2 bb = *(const float2*)&b1[c0];
    float v0 = acc0 * inv + bb.x;
    float v1 = acc1 * inv + bb.y;
    v0 = (v0 > 0.f) ? v0 : (__expf(v0) - 1.f);   // ELU
    v1 = (v1 > 0.f) ? v1 : (__expf(v1) - 1.f);
    h1outu[(size_t)n * 64 + ln] = (uint)f2b(v0) | ((uint)f2b(v1) << 16);
}

// ---------------- layer 2 GEMM (+ fused logits) ----------------
__global__ __launch_bounds__(256) void k_gemm2(
        const ushort* __restrict__ h1outb, const float* __restrict__ W2,
        const float* __restrict__ a_src2, const float* __restrict__ a_dst2,
        ushort* __restrict__ h2b, float* __restrict__ als2, float* __restrict__ ald2) {
    __shared__ float hs[64][129];
    __shared__ float w2s[128][40];
    int t = threadIdx.x;
    int r0 = blockIdx.x * 64;
    for (int i = t; i < F1 * OUT_C; i += 256) w2s[i / 40][i % 40] = W2[i];
    for (int i = t; i < 64 * F1; i += 256) {
        int row = i >> 7, col = i & 127;
        int gr = r0 + row;
        hs[row][col] = (gr < N_NODES) ? b2f(h1outb[(size_t)gr * F1 + col]) : 0.f;
    }
    __syncthreads();
    int row = t >> 2;
    int cb  = (t & 3) * 10;
    float acc[10] = {};
    for (int k = 0; k < F1; k++) {
        float a = hs[row][k];
#pragma unroll
        for (int i = 0; i < 10; i++) acc[i] += a * w2s[k][cb + i];
    }
    int gr = r0 + row;
    float ps = 0.f, pd = 0.f;
#pragma unroll
    for (int i = 0; i < 10; i++) {
        ps += acc[i] * a_src2[cb + i];
        pd += acc[i] * a_dst2[cb + i];
    }
    ps += __shfl_xor(ps, 1); ps += __shfl_xor(ps, 2);
    pd += __shfl_xor(pd, 1); pd += __shfl_xor(pd, 2);
    if ((t & 3) == 0 && gr < N_NODES) { als2[gr] = ps; ald2[gr] = pd; }
    if (gr < N_NODES) {
#pragma unroll
        for (int i = 0; i < 10; i++) h2b[(size_t)gr * OUT_C + cb + i] = f2b(acc[i]);
    }
}

// ---------------- layer 2: fused online-softmax aggregation + log_softmax ----------------
__global__ __launch_bounds__(256) void k_agg2w(
        const int* __restrict__ rp8, const int* __restrict__ esrc,
        const float* __restrict__ als2, const float* __restrict__ ald2,
        const uint* __restrict__ h2u, const float* __restrict__ b2,
        float* __restrict__ out) {
    int w = threadIdx.x >> 6, ln = threadIdx.x & 63;
    int n = blockIdx.x * 4 + w;
    if (n >= N_NODES) return;
    int b = rp8[n << 3], e = rp8[(n << 3) + 8];
    int el = ln & 15;
    float ad = ald2[n];
    bool act = ln < 20;

    float acc0 = 0.f, acc1 = 0.f, ssum = 0.f;
    float m = -1e30f;
    int base = b;

    for (; base + 16 <= e; base += 16) {
        int s_reg = esrc[base + el];
        float v = lrelu(als2[s_reg] + ad);
        float cm = v;
        cm = fmaxf(cm, __shfl_xor(cm, 1));
        cm = fmaxf(cm, __shfl_xor(cm, 2));
        cm = fmaxf(cm, __shfl_xor(cm, 4));
        cm = fmaxf(cm, __shfl_xor(cm, 8));
        float nm = fmaxf(m, cm);
        float sc = __expf(m - nm);
        acc0 *= sc; acc1 *= sc; ssum *= sc;
        m = nm;
        float p = __expf(v - m);
        uint hv[16];
#pragma unroll
        for (int j = 0; j < 16; j++)
            hv[j] = act ? h2u[(size_t)__shfl(s_reg, j) * 20 + ln] : 0u;
#pragma unroll
        for (int j = 0; j < 16; j++) {
            float pj = __shfl(p, j);
            ssum += pj;
            acc0 = fmaf(pj, __uint_as_float(hv[j] << 16), acc0);
            acc1 = fmaf(pj, __uint_as_float(hv[j] & 0xffff0000u), acc1);
        }
    }

    // tail: batched like the fast path
    if (base < e) {
        int cnt = e - base;
        int s_reg = esrc[base + (el < cnt ? el : 0)];
        float v = lrelu(als2[s_reg] + ad);
        if (el >= cnt) v = -1e30f;
        float cm = v;
        cm = fmaxf(cm, __shfl_xor(cm, 1));
        cm = fmaxf(cm, __shfl_xor(cm, 2));
        cm = fmaxf(cm, __shfl_xor(cm, 4));
        cm = fmaxf(cm, __shfl_xor(cm, 8));
        float nm = fmaxf(m, cm);
        float sc = __expf(m - nm);
        acc0 *= sc; acc1 *= sc; ssum *= sc;
        m = nm;
        float p = __expf(v - m);            // 0 for inactive slots
        uint hv[16];
#pragma unroll
        for (int j = 0; j < 16; j++)
            hv[j] = (act && j < cnt) ? h2u[(size_t)__shfl(s_reg, j) * 20 + ln] : 0u;
#pragma unroll
        for (int j = 0; j < 16; j++) {
            float pj = __shfl(p, j);        // 0 for j>=cnt
            ssum += pj;
            acc0 = fmaf(pj, __uint_as_float(hv[j] << 16), acc0);
            acc1 = fmaf(pj, __uint_as_float(hv[j] & 0xffff0000u), acc1);
        }
    }

    float inv = 1.f / ssum;
    int c0 = ln * 2;
    float y0 = -1e30f, y1 = -1e30f;
    if (act) {
        y0 = acc0 * inv + b2[c0];
        y1 = acc1 * inv + b2[c0 + 1];
    }
    float mx = fmaxf(y0, y1);
#pragma unroll
    for (int off = 1; off < 64; off <<= 1) mx = fmaxf(mx, __shfl_xor(mx, off));
    float z = act ? (__expf(y0 - mx) + __expf(y1 - mx)) : 0.f;
#pragma unroll
    for (int off = 1; off < 64; off <<= 1) z += __shfl_xor(z, off);
    float lg = logf(z);
    if (act) {
        float2 o = make_float2(y0 - mx - lg, y1 - mx - lg);
        *(float2*)&out[(size_t)n * OUT_C + c0] = o;
    }
}

extern "C" void kernel_launch(void* const* d_in, const int* in_sizes, int n_in,
                              void* d_out, int out_size, void* d_ws, size_t ws_size,
                              hipStream_t stream) {
    const float* x      = (const float*)d_in[0];
    const int*   eidx   = (const int*)d_in[1];
    const float* W1     = (const float*)d_in[2];
    const float* a_src1 = (const float*)d_in[3];
    const float* a_dst1 = (const float*)d_in[4];
    const float* b1     = (const float*)d_in[5];
    const float* W2     = (const float*)d_in[6];
    const float* a_src2 = (const float*)d_in[7];
    const float* a_dst2 = (const float*)d_in[8];
    const float* b2     = (const float*)d_in[9];
    float* out = (float*)d_out;

    // workspace layout
    float* wf    = (float*)d_ws;
    float* als1  = wf;                   // 200,000
    float* ald1  = wf + 200000;          // 200,000
    float* als2  = wf + 400000;          // 50,000
    float* ald2  = wf + 450000;          // 50,000
    ushort* h1b    = (ushort*)(wf + 500000);   // 6,400,000 ushorts
    ushort* h1outb = h1b + 6400000;            // 6,400,000
    ushort* h2b    = h1outb + 6400000;         // 2,000,000
    ushort* W1T    = h2b + 2000000;            // 32,768
    int* ip      = (int*)(W1T + 32768);
    int* rp8     = ip;                   // 400,001
    int* c8      = ip + 400064;          // 400,384 (8 * P8)
    int* cur8    = ip + 800448;          // 400,384 (contiguous after c8)
    int* esrc    = ip + 1200832;         // 850,000
    int* bs      = ip + 2050832;         // 1,024

    // graph build (XCD-local sub-segmented CSR)
    k_initX   <<<(2 * 8 * P8 + 1023) / 1024, 1024, 0, stream>>>(c8);
    k_degX    <<<(ET + 255) / 256, 256, 0, stream>>>(eidx, c8);
    k_scanA   <<<(NSEG + 1023) / 1024, 1024, 0, stream>>>(c8, rp8, bs);
    k_scanB   <<<1, 1024, 0, stream>>>(bs);
    k_scanC   <<<(NSEG + 1023) / 1024, 1024, 0, stream>>>(rp8, bs);
    k_scatterX<<<(ET + 255) / 256, 256, 0, stream>>>(eidx, rp8, cur8, esrc);

    // layer 1
    k_prepW1<<<(F1 * IN_DIM + 255) / 256, 256, 0, stream>>>(W1, W1T);
    k_gemm1m<<<(N_NODES + 63) / 64, 256, 0, stream>>>(x, W1T, a_src1, a_dst1, h1b, als1, ald1);
    k_agg1w<<<(N_NODES + 3) / 4, 256, 0, stream>>>(rp8, esrc, als1, ald1,
                                                   (const uint*)h1b, b1, (uint*)h1outb);

    // layer 2
    k_gemm2<<<(N_NODES + 63) / 64, 256, 0, stream>>>(h1outb, W2, a_src2, a_dst2, h2b, als2, ald2);
    k_agg2w<<<(N_NODES + 3) / 4, 256, 0, stream>>>(rp8, esrc, als2, ald2,
                                                   (const uint*)h2b, b2, out);
}